// Round 3
// baseline (226.840 us; speedup 1.0000x reference)
//
#include <hip/hip_runtime.h>

// ---------------------------------------------------------------------------
// Gate_16501264351574: conv3x3(256ch -> 64 experts) + sigmoid + top8 + softmax
//   x: [16,256,64,64] f32, gate_w: [64,256,3,3] f32, bias: [64] f32
// out (flat f32): weights [16,8,64,64] | indices-as-f32 [16,8,64,64] | counts[64]
//
// R11: remove LDS staging from the hot kernel. R9/R10 showed the per-chunk
// barrier + single in-order vmcnt stream forces an LLC/HBM round-trip into
// every chunk regardless of issue order (78 vs 100 us, both latency-bound,
// all pipes <20%). New fast path (gated on ws_size at host level):
//   prep_all:  x -> xT[b][66][66][256] f16 (c-contiguous, zero-padded
//              borders, 34 MB, LLC-resident) + wB fragments + counts zero.
//   gate_main2: barrier-free GEMM. A-frags loaded straight from xT
//              (16B/lane, 16 full 64B lines per instr, L1/L2-served),
//              B from wB; 3-tap slot rotation; zero __syncthreads in the
//              K loop -> waves free-run, compiler emits counted vmcnt.
// Fallback (ws too small): R9 structure verbatim (best measured, 78 us).
// ---------------------------------------------------------------------------

typedef _Float16 half8 __attribute__((ext_vector_type(8)));
typedef __attribute__((ext_vector_type(4))) float f32x4;

#define LOG2E 1.44269504f

__device__ __forceinline__ unsigned short f2h_bits(float f) {
    _Float16 h = (_Float16)f;                  // v_cvt_f16_f32, RNE
    unsigned short b;
    __builtin_memcpy(&b, &h, 2);
    return b;
}

constexpr int WB_U4 = 8 * 9 * 4 * 64;          // 18432 uint4 = 294912 B
constexpr size_t XT_BYTES = (size_t)16 * 66 * 66 * 256 * 2;  // 35,684,352
constexpr size_t WS_NEED  = XT_BYTES + (size_t)WB_U4 * 16 + 65536;

// ===========================================================================
// FAST PATH
// ===========================================================================

// prep_all roles by blockIdx: [0,4096) interior transpose+cvt,
// [4096,4161) border zero, [4161,4233) wB fragments (+counts zero).
constexpr int NB_INT = 4096, NB_BOR = 65, NB_WB = 72;
constexpr int PREP_GRID = NB_INT + NB_BOR + NB_WB;   // 4233

__global__ __launch_bounds__(256) void prep_all(
    const float* __restrict__ x, const float* __restrict__ gw,
    _Float16* __restrict__ xT, unsigned short* __restrict__ wB,
    float* __restrict__ out) {
    const int blk = blockIdx.x, tid = threadIdx.x;
    if (blk < NB_INT) {
        // interior: thread = (b, h, c16, w); reads coalesced along w.
        int gid = blk * 256 + tid;
        int w = gid & 63, c16 = (gid >> 6) & 15, h = (gid >> 10) & 63, b = gid >> 16;
        int c0 = c16 * 16;
        const float* src = x + ((b * 256 + c0) * 64 + h) * 64 + w;
        float v[16];
#pragma unroll
        for (int j = 0; j < 16; ++j) v[j] = src[j * 4096];
        uint4 p0, p1;
        p0.x = (unsigned)f2h_bits(v[0])  | ((unsigned)f2h_bits(v[1])  << 16);
        p0.y = (unsigned)f2h_bits(v[2])  | ((unsigned)f2h_bits(v[3])  << 16);
        p0.z = (unsigned)f2h_bits(v[4])  | ((unsigned)f2h_bits(v[5])  << 16);
        p0.w = (unsigned)f2h_bits(v[6])  | ((unsigned)f2h_bits(v[7])  << 16);
        p1.x = (unsigned)f2h_bits(v[8])  | ((unsigned)f2h_bits(v[9])  << 16);
        p1.y = (unsigned)f2h_bits(v[10]) | ((unsigned)f2h_bits(v[11]) << 16);
        p1.z = (unsigned)f2h_bits(v[12]) | ((unsigned)f2h_bits(v[13]) << 16);
        p1.w = (unsigned)f2h_bits(v[14]) | ((unsigned)f2h_bits(v[15]) << 16);
        int site = (b * 66 + h + 1) * 66 + (w + 1);
        uint4* dst = (uint4*)xT + site * 32 + c16 * 2;
        dst[0] = p0; dst[1] = p1;
    } else if (blk < NB_INT + NB_BOR) {
        // border zero: 4160 sites x 512B; thread zeroes 128B.
        int t = (blk - NB_INT) * 256 + tid;
        int site = t >> 2, part = t & 3;     // site < 4160 exactly
        int sb = site / 260, s = site - sb * 260;
        int hp, wp;
        if (s < 132) { hp = (s >= 66) ? 65 : 0; wp = (s >= 66) ? (s - 66) : s; }
        else         { int s2 = s - 132; hp = 1 + (s2 >> 1); wp = (s2 & 1) * 65; }
        uint4 z = {0u, 0u, 0u, 0u};
        uint4* dst = (uint4*)xT + ((sb * 66 + hp) * 66 + wp) * 32 + part * 8;
#pragma unroll
        for (int k = 0; k < 8; ++k) dst[k] = z;
    } else {
        // wB: chunk-major f16 B-fragments (same layout as before).
        int wblk = blk - (NB_INT + NB_BOR);
        if (wblk == 0 && tid < 64) out[1048576 + tid] = 0.f;
        int g = wblk * 256 + tid;            // < WB_U4 exactly
        int lane = g & 63;
        int nt   = (g >> 6) & 3;
        int rest = g >> 8;                   // q*9 + t
        int t = rest % 9, q = rest / 9;
        int e  = nt * 16 + (lane & 15);
        int c0 = q * 32 + (lane >> 4) * 8;
        unsigned short o[8];
#pragma unroll
        for (int j = 0; j < 8; ++j)
            o[j] = f2h_bits(gw[(e * 256 + c0 + j) * 9 + t]);
        uint4 pk;
        pk.x = (unsigned)o[0] | ((unsigned)o[1] << 16);
        pk.y = (unsigned)o[2] | ((unsigned)o[3] << 16);
        pk.z = (unsigned)o[4] | ((unsigned)o[5] << 16);
        pk.w = (unsigned)o[6] | ((unsigned)o[7] << 16);
        ((uint4*)wB)[g] = pk;
    }
}

// ---------------------------------------------------------------------------
// gate_main2: grid 1024 (b = blk&15 -> XCD partition: each XCD sees 2 images,
// all rows -> 4.5MB/XCD L2 working set). Block = one (b, row): 4 waves,
// wave = 32pos x 32exp (ph = rw>>1, eh = rw&1). No LDS in K loop; one
// barrier before the top-8 epilogue.
// ---------------------------------------------------------------------------
constexpr int SSTR = 68;                       // fp32 score row stride

__global__ __launch_bounds__(256, 4) void gate_main2(
    const _Float16* __restrict__ xT, const float* __restrict__ bias,
    const unsigned short* __restrict__ wB, float* __restrict__ out) {
    __shared__ float scf[64 * SSTR];           // 17408 B
    __shared__ float bias_s[64];
    __shared__ int   hist[64];

    const int tid  = threadIdx.x;
    const int lane = tid & 63;
    const int rw   = tid >> 6;
    const int blk  = blockIdx.x;
    const int b    = blk & 15;
    const int r    = blk >> 4;                 // output row 0..63

    if (tid < 64) { bias_s[tid] = bias[tid]; hist[tid] = 0; }

    const int ph = rw >> 1, eh = rw & 1;

    // A pointers: 6 of them (3 kh x 2 m-tiles); wp(kw=0) = ph*32+m*16+(lane&15),
    // kw adds +256 f16 (imm 512B); chunk q adds +32 f16 (bump per chunk).
    const _Float16* pa[3][2];
#pragma unroll
    for (int kh = 0; kh < 3; ++kh)
#pragma unroll
        for (int m = 0; m < 2; ++m)
            pa[kh][m] = xT + (size_t)(((b * 66 + r + kh) * 66) +
                              ph * 32 + m * 16 + (lane & 15)) * 256 + (lane >> 4) * 8;

    // B pointer: monotonic through the whole kernel, +256 uint4 per tap.
    const uint4* bptr = (const uint4*)wB + eh * 128 + lane;

    half8 Aa[3][2];
    uint4 Bb[3][2];
    f32x4 acc[2][2];
#pragma unroll
    for (int mt = 0; mt < 2; ++mt)
#pragma unroll
        for (int nt = 0; nt < 2; ++nt) acc[mt][nt] = (f32x4){0.f, 0.f, 0.f, 0.f};

    auto LD = [&](int t, int slot) {           // t literal at every call site
        const int kh = t / 3, kw = t % 3;
#pragma unroll
        for (int m = 0; m < 2; ++m)
            Aa[slot][m] = *(const half8*)(pa[kh][m] + kw * 256);
#pragma unroll
        for (int nt = 0; nt < 2; ++nt) Bb[slot][nt] = bptr[nt * 64];
        bptr += 256;
    };
    auto mfma_tap = [&](int slot) {
#pragma unroll
        for (int nt = 0; nt < 2; ++nt) {
            half8 bfr;
            __builtin_memcpy(&bfr, &Bb[slot][nt], 16);
#pragma unroll
            for (int mt = 0; mt < 2; ++mt)
                acc[mt][nt] = __builtin_amdgcn_mfma_f32_16x16x32_f16(
                    Aa[slot][mt], bfr, acc[mt][nt], 0, 0, 0);
        }
    };

    // prologue: taps 0..2 of chunk 0
    LD(0, 0); LD(1, 1); LD(2, 2);

    // K loop: 8 chunks x 9 taps, lead-3 rotation, NO barriers.
#pragma unroll 1
    for (int q = 0; q < 8; ++q) {
        mfma_tap(0); LD(3, 0);
        mfma_tap(1); LD(4, 1);
        mfma_tap(2); LD(5, 2);
        mfma_tap(0); LD(6, 0);
        mfma_tap(1); LD(7, 1);
        mfma_tap(2); LD(8, 2);
#pragma unroll
        for (int kh = 0; kh < 3; ++kh)
#pragma unroll
            for (int m = 0; m < 2; ++m) pa[kh][m] += 32;   // next chunk
        mfma_tap(0); LD(0, 0);                 // next-chunk taps 0..2
        mfma_tap(1); LD(1, 1);                 // (tail overreads land in wB
        mfma_tap(2); LD(2, 2);                 //  slack, never consumed)
    }

    // ---- epilogue: sigmoid -> fp32 scores in LDS ---------------------------
#pragma unroll
    for (int mt = 0; mt < 2; ++mt)
#pragma unroll
        for (int nt = 0; nt < 2; ++nt)
#pragma unroll
            for (int rr = 0; rr < 4; ++rr) {
                float v = acc[mt][nt][rr];
                float s = 1.f / (1.f + __builtin_amdgcn_exp2f(-v * LOG2E));
                int p = ph * 32 + mt * 16 + ((lane >> 4) << 2) + rr;
                int e = eh * 32 + nt * 16 + (lane & 15);
                scf[p * SSTR + e] = s;
            }
    __syncthreads();

    if (tid < 64) {
        const float* row = scf + tid * SSTR;
        float tv[8];
        int   ti[8];
#pragma unroll
        for (int k = 0; k < 8; ++k) { tv[k] = -3.0e38f; ti[k] = 0; }
#pragma unroll
        for (int j4 = 0; j4 < 16; ++j4) {
            f32x4 blkv = *(const f32x4*)(row + j4 * 4);
#pragma unroll
            for (int j = 0; j < 4; ++j) {
                int   e  = j4 * 4 + j;
                float bs = blkv[j] + bias_s[e];
                if (bs > tv[7]) {
                    tv[7] = bs; ti[7] = e;
#pragma unroll
                    for (int k = 7; k > 0; --k) {
                        float fa = tv[k - 1], fb = tv[k];
                        int   ia = ti[k - 1], ib = ti[k];
                        bool  sw = fb > fa;
                        tv[k - 1] = sw ? fb : fa; tv[k] = sw ? fa : fb;
                        ti[k - 1] = sw ? ib : ia; ti[k] = sw ? ia : ib;
                    }
                }
            }
        }
        float u[8], mx = -3.0e38f;
#pragma unroll
        for (int k = 0; k < 8; ++k) { u[k] = tv[k] - bias_s[ti[k]]; mx = fmaxf(mx, u[k]); }
        float ex[8], sum = 0.f;
#pragma unroll
        for (int k = 0; k < 8; ++k) { ex[k] = __builtin_amdgcn_exp2f((u[k] - mx) * LOG2E); sum += ex[k]; }
        float inv = 1.f / sum;

        int obase = b * 32768 + r * 64 + tid;
#pragma unroll
        for (int k = 0; k < 8; ++k) {
            out[obase + k * 4096]          = ex[k] * inv;
            out[524288 + obase + k * 4096] = (float)ti[k];
            atomicAdd(&hist[ti[k]], 1);
        }
    }
    __syncthreads();
    if (tid < 64) atomicAdd(out + 1048576 + tid, (float)hist[tid]);
}

// ===========================================================================
// FALLBACK PATH (R9 verbatim: best measured, gate_main ~78 us)
// ===========================================================================

__global__ __launch_bounds__(256) void gate_prep(const float* __restrict__ gw,
                                                 unsigned short* __restrict__ wB,
                                                 float* __restrict__ out) {
    int g = blockIdx.x * 256 + threadIdx.x;
    if (blockIdx.x == 0 && threadIdx.x < 64) out[1048576 + threadIdx.x] = 0.f;
    if (g >= WB_U4) return;
    int lane = g & 63;
    int nt   = (g >> 6) & 3;
    int rest = g >> 8;
    int t = rest % 9, q = rest / 9;
    int e  = nt * 16 + (lane & 15);
    int c0 = q * 32 + (lane >> 4) * 8;
    unsigned short o[8];
#pragma unroll
    for (int j = 0; j < 8; ++j)
        o[j] = f2h_bits(gw[(e * 256 + c0 + j) * 9 + t]);
    uint4 pk;
    pk.x = (unsigned)o[0] | ((unsigned)o[1] << 16);
    pk.y = (unsigned)o[2] | ((unsigned)o[3] << 16);
    pk.z = (unsigned)o[4] | ((unsigned)o[5] << 16);
    pk.w = (unsigned)o[6] | ((unsigned)o[7] << 16);
    ((uint4*)wB)[g] = pk;
}

constexpr int CSTR = 40;
constexpr int SLAB = 3 * 66 * CSTR;

__global__ __launch_bounds__(256, 4) void gate_main_fb(
    const float* __restrict__ x, const float* __restrict__ bias,
    const unsigned short* __restrict__ wB, float* __restrict__ out) {
    __shared__ unsigned short xs[2 * SLAB];
    __shared__ float bias_s[64];
    __shared__ int   hist[64];

    const int tid  = threadIdx.x;
    const int lane = tid & 63;
    const int rw   = tid >> 6;
    const int blk  = blockIdx.x;
    const int b    = blk & 15;
    const int r    = blk >> 4;

    if (tid < 64) { bias_s[tid] = bias[tid]; hist[tid] = 0; }
    {
        uint4 z = {0u, 0u, 0u, 0u};
        uint4* p = (uint4*)xs;
#pragma unroll
        for (int i = 0; i < 8; ++i) {
            int idx = tid + i * 256;
            if (idx < 2 * SLAB / 8) p[idx] = z;
        }
    }

    bool tOk[4];
    int  tSrc[4], tDst[4];
#pragma unroll
    for (int i = 0; i < 4; ++i) {
        int T = tid + i * 256;
        bool ex = (T < 792);
        int chh = T / 198, s = T - chh * 198;
        int row2 = s / 66, wp = s - row2 * 66;
        int gr = r - 1 + row2, gwc = wp - 1;
        tOk[i]  = ex && (gr >= 0) && (gr < 64) && (gwc >= 0) && (gwc < 64);
        tSrc[i] = ((b * 256 + chh * 8) * 64 + gr) * 64 + gwc;
        tDst[i] = (row2 * 66 + wp) * CSTR + chh * 8;
    }

    float tb[4][8];
    auto issueT = [&](int i, int dq) {
        if (tOk[i]) {
            const float* p = x + tSrc[i] + dq * 131072;
#pragma unroll
            for (int u = 0; u < 8; ++u) tb[i][u] = p[u * 4096];
        }
    };
    auto commitT = [&](int i, unsigned short* dst) {
        if (tOk[i]) {
            uint4 pk;
            pk.x = (unsigned)f2h_bits(tb[i][0]) | ((unsigned)f2h_bits(tb[i][1]) << 16);
            pk.y = (unsigned)f2h_bits(tb[i][2]) | ((unsigned)f2h_bits(tb[i][3]) << 16);
            pk.z = (unsigned)f2h_bits(tb[i][4]) | ((unsigned)f2h_bits(tb[i][5]) << 16);
            pk.w = (unsigned)f2h_bits(tb[i][6]) | ((unsigned)f2h_bits(tb[i][7]) << 16);
            *(uint4*)(dst + tDst[i]) = pk;
        }
    };

    const int ph = rw >> 1, eh = rw & 1;
    half8 Aa[3][2];
    uint4 Bb[3][2];
    auto prefA = [&](const unsigned short* buf, int t, int slot) {
        const int kh = t / 3, kw = t % 3;
        const unsigned short* abase =
            buf + (kh * 66 + ph * 32 + (lane & 15) + kw) * CSTR + (lane >> 4) * 8;
#pragma unroll
        for (int mt = 0; mt < 2; ++mt)
            Aa[slot][mt] = *(const half8*)(abase + mt * 16 * CSTR);
    };
    auto prefB = [&](int T9, int slot) {
        const uint4* bp = (const uint4*)wB + (T9 * 4 + eh * 2) * 64 + lane;
#pragma unroll
        for (int nt = 0; nt < 2; ++nt) Bb[slot][nt] = bp[nt * 64];
    };

    f32x4 acc[2][2];
#pragma unroll
    for (int mt = 0; mt < 2; ++mt)
#pragma unroll
        for (int nt = 0; nt < 2; ++nt) acc[mt][nt] = (f32x4){0.f, 0.f, 0.f, 0.f};

    auto mfma_tap = [&](int slot) {
#pragma unroll
        for (int nt = 0; nt < 2; ++nt) {
            half8 bfr;
            __builtin_memcpy(&bfr, &Bb[slot][nt], 16);
#pragma unroll
            for (int mt = 0; mt < 2; ++mt)
                acc[mt][nt] = __builtin_amdgcn_mfma_f32_16x16x32_f16(
                    Aa[slot][mt], bfr, acc[mt][nt], 0, 0, 0);
        }
    };

    __syncthreads();
    issueT(0, 0); issueT(1, 0); issueT(2, 0); issueT(3, 0);
    commitT(0, xs); commitT(1, xs); commitT(2, xs); commitT(3, xs);
    issueT(0, 1); issueT(1, 1); issueT(2, 1); issueT(3, 1);
    prefB(0, 0); prefB(1, 1); prefB(2, 2);
    __syncthreads();

#pragma unroll 1
    for (int q = 0; q < 8; ++q) {
        const unsigned short* cur = xs + (q & 1) * SLAB;
        unsigned short*       nxt = xs + ((q + 1) & 1) * SLAB;
        const int  T0  = q * 9;
        const bool cmt = (q < 7);
        const bool iss = (q < 6);

        prefA(cur, 0, 0); prefA(cur, 1, 1);
        mfma_tap(0); prefB(T0 + 3, 0); prefA(cur, 2, 2);
        mfma_tap(1); prefB(T0 + 4, 1); prefA(cur, 3, 0);
        if (cmt) { commitT(0, nxt); commitT(1, nxt); }
        mfma_tap(2); prefB(T0 + 5, 2); prefA(cur, 4, 1);
        mfma_tap(0); prefB(T0 + 6, 0); prefA(cur, 5, 2);
        if (cmt) { commitT(2, nxt); commitT(3, nxt); }
        mfma_tap(1); prefB(T0 + 7, 1); prefA(cur, 6, 0);
        mfma_tap(2); prefB(T0 + 8, 2); prefA(cur, 7, 1);
        __builtin_amdgcn_sched_barrier(0);
        if (iss) { issueT(0, q + 2); issueT(1, q + 2); issueT(2, q + 2); issueT(3, q + 2); }
        __builtin_amdgcn_sched_barrier(0);
        mfma_tap(0); if (cmt) prefB(T0 + 9, 0);  prefA(cur, 8, 2);
        mfma_tap(1); if (cmt) prefB(T0 + 10, 1);
        mfma_tap(2); if (cmt) prefB(T0 + 11, 2);
        __syncthreads();
    }

    float* scf2 = (float*)xs;
#pragma unroll
    for (int mt = 0; mt < 2; ++mt)
#pragma unroll
        for (int nt = 0; nt < 2; ++nt)
#pragma unroll
            for (int rr = 0; rr < 4; ++rr) {
                float v = acc[mt][nt][rr];
                float s = 1.f / (1.f + __builtin_amdgcn_exp2f(-v * LOG2E));
                int p = ph * 32 + mt * 16 + ((lane >> 4) << 2) + rr;
                int e = eh * 32 + nt * 16 + (lane & 15);
                scf2[p * SSTR + e] = s;
            }
    __syncthreads();

    if (tid < 64) {
        const float* row = scf2 + tid * SSTR;
        float tv[8];
        int   ti[8];
#pragma unroll
        for (int k = 0; k < 8; ++k) { tv[k] = -3.0e38f; ti[k] = 0; }
#pragma unroll
        for (int j4 = 0; j4 < 16; ++j4) {
            f32x4 blkv = *(const f32x4*)(row + j4 * 4);
#pragma unroll
            for (int j = 0; j < 4; ++j) {
                int   e  = j4 * 4 + j;
                float bs = blkv[j] + bias_s[e];
                if (bs > tv[7]) {
                    tv[7] = bs; ti[7] = e;
#pragma unroll
                    for (int k = 7; k > 0; --k) {
                        float fa = tv[k - 1], fb = tv[k];
                        int   ia = ti[k - 1], ib = ti[k];
                        bool  sw = fb > fa;
                        tv[k - 1] = sw ? fb : fa; tv[k] = sw ? fa : fb;
                        ti[k - 1] = sw ? ib : ia; ti[k] = sw ? ia : ib;
                    }
                }
            }
        }
        float u[8], mx = -3.0e38f;
#pragma unroll
        for (int k = 0; k < 8; ++k) { u[k] = tv[k] - bias_s[ti[k]]; mx = fmaxf(mx, u[k]); }
        float ex[8], sum = 0.f;
#pragma unroll
        for (int k = 0; k < 8; ++k) { ex[k] = __builtin_amdgcn_exp2f((u[k] - mx) * LOG2E); sum += ex[k]; }
        float inv = 1.f / sum;

        int obase = b * 32768 + r * 64 + tid;
#pragma unroll
        for (int k = 0; k < 8; ++k) {
            out[obase + k * 4096]          = ex[k] * inv;
            out[524288 + obase + k * 4096] = (float)ti[k];
            atomicAdd(&hist[ti[k]], 1);
        }
    }
    __syncthreads();
    if (tid < 64) atomicAdd(out + 1048576 + tid, (float)hist[tid]);
}

// ---------------------------------------------------------------------------
extern "C" void kernel_launch(void* const* d_in, const int* in_sizes, int n_in,
                              void* d_out, int out_size, void* d_ws, size_t ws_size,
                              hipStream_t stream) {
    const float* x    = (const float*)d_in[0];
    const float* gw   = (const float*)d_in[1];
    const float* bias = (const float*)d_in[2];
    float* out = (float*)d_out;

    if (ws_size >= WS_NEED) {
        _Float16* xT = (_Float16*)d_ws;
        unsigned short* wB = (unsigned short*)((char*)d_ws + XT_BYTES);
        prep_all<<<PREP_GRID, 256, 0, stream>>>(x, gw, xT, wB, out);
        gate_main2<<<1024, 256, 0, stream>>>(xT, bias, wB, out);
    } else {
        unsigned short* wB = (unsigned short*)d_ws;
        gate_prep<<<72, 256, 0, stream>>>(gw, wB, out);
        gate_main_fb<<<1024, 256, 0, stream>>>(x, bias, wB, out);
    }
}

// Round 4
// 194.849 us; speedup vs baseline: 1.1642x; 1.1642x over previous
//
#include <hip/hip_runtime.h>

// ---------------------------------------------------------------------------
// Gate_16501264351574: conv3x3(256ch -> 64 experts) + sigmoid + top8 + softmax
//   x: [16,256,64,64] f32, gate_w: [64,256,3,3] f32, bias: [64] f32
// out (flat f32): weights [16,8,64,64] | indices-as-f32 [16,8,64,64] | counts[64]
//
// R12: fix R11's two latency defects, keep the precompute.
//  (1) xT2 layout [b][66row][8q][66w][32c] f16: A-fragment loads become
//      64 lanes x 16B = 1KB CONTIGUOUS (R11's [site][256c] scattered each
//      load over 16 lines 512B apart -> L1/MSHR saturation, no TLP overlap,
//      MfmaUtil 6%). Per-chunk A footprint ~13KB -> L1-resident; kw/kh
//      taps re-hit L1 lines.
//  (2) asymmetric pipeline: A slots 3-deep (L1-hot, ~150cy lead ok),
//      B slots 6-deep (~300cy lead covers L2), via 2-chunk-unrolled body
//      (18 groups, static slots j%3 / j%6). ~105 VGPR < 128 cap.
// Barrier-free K loop (no __syncthreads until epilogue), 1024 blocks,
// b=blk&15 -> XCD pairing, 4 blocks/CU.
// Fallback (ws too small): R9 structure verbatim.
// ---------------------------------------------------------------------------

typedef _Float16 half8 __attribute__((ext_vector_type(8)));
typedef __attribute__((ext_vector_type(4))) float f32x4;

#define LOG2E 1.44269504f

__device__ __forceinline__ unsigned short f2h_bits(float f) {
    _Float16 h = (_Float16)f;                  // v_cvt_f16_f32, RNE
    unsigned short b;
    __builtin_memcpy(&b, &h, 2);
    return b;
}

constexpr int WB_U4 = 8 * 9 * 4 * 64;          // 18432 uint4 = 294912 B
constexpr size_t XT_BYTES = (size_t)16 * 66 * 8 * 66 * 32 * 2;  // 35,684,352
constexpr size_t WS_NEED  = XT_BYTES + (size_t)WB_U4 * 16 + 262144;

// ===========================================================================
// FAST PATH
// ===========================================================================

// prep_all2 roles by blockIdx: [0,4096) interior transpose+cvt,
// [4096,4226) border zero, [4226,4298) wB fragments (+counts zero).
constexpr int NB_INT = 4096, NB_BOR = 130, NB_WB = 72;
constexpr int PREP_GRID = NB_INT + NB_BOR + NB_WB;   // 4298

__global__ __launch_bounds__(256) void prep_all2(
    const float* __restrict__ x, const float* __restrict__ gw,
    _Float16* __restrict__ xT, unsigned short* __restrict__ wB,
    float* __restrict__ out) {
    const int blk = blockIdx.x, tid = threadIdx.x;
    if (blk < NB_INT) {
        // interior: thread = (b, h, c16, w); reads coalesced along w.
        int gid = blk * 256 + tid;
        int w = gid & 63, c16 = (gid >> 6) & 15, h = (gid >> 10) & 63, b = gid >> 16;
        int c0 = c16 * 16;
        const float* src = x + ((b * 256 + c0) * 64 + h) * 64 + w;
        float v[16];
#pragma unroll
        for (int j = 0; j < 16; ++j) v[j] = src[j * 4096];
        uint4 p0, p1;
        p0.x = (unsigned)f2h_bits(v[0])  | ((unsigned)f2h_bits(v[1])  << 16);
        p0.y = (unsigned)f2h_bits(v[2])  | ((unsigned)f2h_bits(v[3])  << 16);
        p0.z = (unsigned)f2h_bits(v[4])  | ((unsigned)f2h_bits(v[5])  << 16);
        p0.w = (unsigned)f2h_bits(v[6])  | ((unsigned)f2h_bits(v[7])  << 16);
        p1.x = (unsigned)f2h_bits(v[8])  | ((unsigned)f2h_bits(v[9])  << 16);
        p1.y = (unsigned)f2h_bits(v[10]) | ((unsigned)f2h_bits(v[11]) << 16);
        p1.z = (unsigned)f2h_bits(v[12]) | ((unsigned)f2h_bits(v[13]) << 16);
        p1.w = (unsigned)f2h_bits(v[14]) | ((unsigned)f2h_bits(v[15]) << 16);
        // xT2 index: (((b*66 + h+1)*8 + q)*66 + (w+1))*32 + (c16&1)*16
        int q = c16 >> 1;
        size_t idx = ((((size_t)b * 66 + h + 1) * 8 + q) * 66 + (w + 1)) * 32
                     + (c16 & 1) * 16;
        uint4* dst = (uint4*)(xT + idx);
        dst[0] = p0; dst[1] = p1;
    } else if (blk < NB_INT + NB_BOR) {
        // border zero: 4160 sites x 8 q-slices x 64B; thread zeroes 64B.
        int t = (blk - NB_INT) * 256 + tid;    // < 33280 exactly
        int q = t & 7, site = t >> 3;          // site < 4160
        int sb = site / 260, s = site - sb * 260;
        int hp, wp;
        if (s < 132) { hp = (s >= 66) ? 65 : 0; wp = (s >= 66) ? (s - 66) : s; }
        else         { int s2 = s - 132; hp = 1 + (s2 >> 1); wp = (s2 & 1) * 65; }
        uint4 z = {0u, 0u, 0u, 0u};
        size_t idx = ((((size_t)sb * 66 + hp) * 8 + q) * 66 + wp) * 32;
        uint4* dst = (uint4*)(xT + idx);
#pragma unroll
        for (int k = 0; k < 4; ++k) dst[k] = z;
    } else {
        // wB: chunk-major f16 B-fragments (same layout as before).
        int wblk = blk - (NB_INT + NB_BOR);
        if (wblk == 0 && tid < 64) out[1048576 + tid] = 0.f;
        int g = wblk * 256 + tid;              // < WB_U4 exactly
        int lane = g & 63;
        int nt   = (g >> 6) & 3;
        int rest = g >> 8;                     // q*9 + t
        int t = rest % 9, q = rest / 9;
        int e  = nt * 16 + (lane & 15);
        int c0 = q * 32 + (lane >> 4) * 8;
        unsigned short o[8];
#pragma unroll
        for (int j = 0; j < 8; ++j)
            o[j] = f2h_bits(gw[(e * 256 + c0 + j) * 9 + t]);
        uint4 pk;
        pk.x = (unsigned)o[0] | ((unsigned)o[1] << 16);
        pk.y = (unsigned)o[2] | ((unsigned)o[3] << 16);
        pk.z = (unsigned)o[4] | ((unsigned)o[5] << 16);
        pk.w = (unsigned)o[6] | ((unsigned)o[7] << 16);
        ((uint4*)wB)[g] = pk;
    }
}

// ---------------------------------------------------------------------------
// gate_main3: grid 1024, block = one (b=blk&15, r=blk>>4): 4 waves,
// wave = 32pos x 32exp (ph = rw>>1, eh = rw&1). Barrier-free K loop,
// A slots 3-deep / B slots 6-deep, 2-chunk-unrolled body.
// ---------------------------------------------------------------------------
constexpr int SSTR = 68;                       // fp32 score row stride
constexpr int QSTR = 66 * 32;                  // f16 per (row, q-slice) = 2112

__global__ __launch_bounds__(256, 4) void gate_main3(
    const _Float16* __restrict__ xT, const float* __restrict__ bias,
    const unsigned short* __restrict__ wB, float* __restrict__ out) {
    __shared__ float scf[64 * SSTR];           // 17408 B
    __shared__ float bias_s[64];
    __shared__ int   hist[64];

    const int tid  = threadIdx.x;
    const int lane = tid & 63;
    const int rw   = tid >> 6;
    const int blk  = blockIdx.x;
    const int b    = blk & 15;
    const int r    = blk >> 4;                 // output row 0..63

    if (tid < 64) { bias_s[tid] = bias[tid]; hist[tid] = 0; }

    const int ph = rw >> 1, eh = rw & 1;

    // A pointers, one per kh. Fragment addr(m, kw, q) = pa[kh]
    //   + q*QSTR (pointer bump per chunk) + (m*16 + kw)*32 (imm <= 1152B).
    // Base wp0 = ph*32 + (lane&15); channel sub-offset (lane>>4)*8.
    const _Float16* pa[3];
#pragma unroll
    for (int kh = 0; kh < 3; ++kh)
        pa[kh] = xT + ((((size_t)b * 66 + r + kh) * 8) * 66
                       + ph * 32 + (lane & 15)) * 32 + (lane >> 4) * 8;

    // B pointer: monotonic, +256 uint4 per tap.
    const uint4* bptr = (const uint4*)wB + eh * 128 + lane;

    half8 Aa[3][2];
    uint4 Bb[6][2];
    f32x4 acc[2][2];
#pragma unroll
    for (int mt = 0; mt < 2; ++mt)
#pragma unroll
        for (int nt = 0; nt < 2; ++nt) acc[mt][nt] = (f32x4){0.f, 0.f, 0.f, 0.f};

    auto lda = [&](int t, int slot) {          // t, slot literals at call sites
        const int kh = t / 3, kw = t % 3;
#pragma unroll
        for (int m = 0; m < 2; ++m)
            Aa[slot][m] = *(const half8*)(pa[kh] + (m * 16 + kw) * 32);
    };
    auto ldb = [&](int slot) {
#pragma unroll
        for (int nt = 0; nt < 2; ++nt) Bb[slot][nt] = bptr[nt * 64];
        bptr += 256;
    };
    auto mt_ = [&](int as, int bs) {
#pragma unroll
        for (int nt = 0; nt < 2; ++nt) {
            half8 bfr;
            __builtin_memcpy(&bfr, &Bb[bs][nt], 16);
#pragma unroll
            for (int m = 0; m < 2; ++m)
                acc[m][nt] = __builtin_amdgcn_mfma_f32_16x16x32_f16(
                    Aa[as][m], bfr, acc[m][nt], 0, 0, 0);
        }
    };
    auto bump = [&]() {
#pragma unroll
        for (int kh = 0; kh < 3; ++kh) pa[kh] += QSTR;
    };

    // prologue: A taps 0..2 -> slots 0..2; B taps 0..5 -> slots 0..5.
    lda(0, 0); lda(1, 1); lda(2, 2);
    ldb(0); ldb(1); ldb(2); ldb(3); ldb(4); ldb(5);

    // body: 4 iterations x 2 chunks (18 tap-groups). Group j consumes
    // global tap j (a-slot j%3, b-slot j%6), reloads a-slot with tap j+3,
    // b-slot with tap j+6 (bptr monotonic).
#pragma unroll 1
    for (int i = 0; i < 4; ++i) {
        mt_(0, 0); lda(3, 0); ldb(0);
        mt_(1, 1); lda(4, 1); ldb(1);
        mt_(2, 2); lda(5, 2); ldb(2);
        mt_(0, 3); lda(6, 0); ldb(3);
        mt_(1, 4); lda(7, 1); ldb(4);
        mt_(2, 5); lda(8, 2); ldb(5);
        bump();                                // pa -> chunk c+1
        mt_(0, 0); lda(0, 0); ldb(0);
        mt_(1, 1); lda(1, 1); ldb(1);
        mt_(2, 2); lda(2, 2); ldb(2);
        mt_(0, 3); lda(3, 0); ldb(3);
        mt_(1, 4); lda(4, 1); ldb(4);
        mt_(2, 5); lda(5, 2); ldb(5);
        mt_(0, 0); lda(6, 0); ldb(0);
        mt_(1, 1); lda(7, 1); ldb(1);
        mt_(2, 2); lda(8, 2); ldb(2);
        bump();                                // pa -> chunk c+2
        mt_(0, 3); lda(0, 0); ldb(3);
        mt_(1, 4); lda(1, 1); ldb(4);
        mt_(2, 5); lda(2, 2); ldb(5);
        // final iter: trailing loads read chunk-8 / wB-tail garbage inside
        // the workspace (never consumed) -- safe by WS slack.
    }

    // ---- epilogue: sigmoid -> fp32 scores in LDS ---------------------------
#pragma unroll
    for (int mt = 0; mt < 2; ++mt)
#pragma unroll
        for (int nt = 0; nt < 2; ++nt)
#pragma unroll
            for (int rr = 0; rr < 4; ++rr) {
                float v = acc[mt][nt][rr];
                float s = 1.f / (1.f + __builtin_amdgcn_exp2f(-v * LOG2E));
                int p = ph * 32 + mt * 16 + ((lane >> 4) << 2) + rr;
                int e = eh * 32 + nt * 16 + (lane & 15);
                scf[p * SSTR + e] = s;
            }
    __syncthreads();

    if (tid < 64) {
        const float* row = scf + tid * SSTR;
        float tv[8];
        int   ti[8];
#pragma unroll
        for (int k = 0; k < 8; ++k) { tv[k] = -3.0e38f; ti[k] = 0; }
#pragma unroll
        for (int j4 = 0; j4 < 16; ++j4) {
            f32x4 blkv = *(const f32x4*)(row + j4 * 4);
#pragma unroll
            for (int j = 0; j < 4; ++j) {
                int   e  = j4 * 4 + j;
                float bs = blkv[j] + bias_s[e];
                if (bs > tv[7]) {
                    tv[7] = bs; ti[7] = e;
#pragma unroll
                    for (int k = 7; k > 0; --k) {
                        float fa = tv[k - 1], fb = tv[k];
                        int   ia = ti[k - 1], ib = ti[k];
                        bool  sw = fb > fa;
                        tv[k - 1] = sw ? fb : fa; tv[k] = sw ? fa : fb;
                        ti[k - 1] = sw ? ib : ia; ti[k] = sw ? ia : ib;
                    }
                }
            }
        }
        float u[8], mx = -3.0e38f;
#pragma unroll
        for (int k = 0; k < 8; ++k) { u[k] = tv[k] - bias_s[ti[k]]; mx = fmaxf(mx, u[k]); }
        float ex[8], sum = 0.f;
#pragma unroll
        for (int k = 0; k < 8; ++k) { ex[k] = __builtin_amdgcn_exp2f((u[k] - mx) * LOG2E); sum += ex[k]; }
        float inv = 1.f / sum;

        int obase = b * 32768 + r * 64 + tid;
#pragma unroll
        for (int k = 0; k < 8; ++k) {
            out[obase + k * 4096]          = ex[k] * inv;
            out[524288 + obase + k * 4096] = (float)ti[k];
            atomicAdd(&hist[ti[k]], 1);
        }
    }
    __syncthreads();
    if (tid < 64) atomicAdd(out + 1048576 + tid, (float)hist[tid]);
}

// ===========================================================================
// FALLBACK PATH (R9 verbatim: best measured, gate_main ~78 us)
// ===========================================================================

__global__ __launch_bounds__(256) void gate_prep(const float* __restrict__ gw,
                                                 unsigned short* __restrict__ wB,
                                                 float* __restrict__ out) {
    int g = blockIdx.x * 256 + threadIdx.x;
    if (blockIdx.x == 0 && threadIdx.x < 64) out[1048576 + threadIdx.x] = 0.f;
    if (g >= WB_U4) return;
    int lane = g & 63;
    int nt   = (g >> 6) & 3;
    int rest = g >> 8;
    int t = rest % 9, q = rest / 9;
    int e  = nt * 16 + (lane & 15);
    int c0 = q * 32 + (lane >> 4) * 8;
    unsigned short o[8];
#pragma unroll
    for (int j = 0; j < 8; ++j)
        o[j] = f2h_bits(gw[(e * 256 + c0 + j) * 9 + t]);
    uint4 pk;
    pk.x = (unsigned)o[0] | ((unsigned)o[1] << 16);
    pk.y = (unsigned)o[2] | ((unsigned)o[3] << 16);
    pk.z = (unsigned)o[4] | ((unsigned)o[5] << 16);
    pk.w = (unsigned)o[6] | ((unsigned)o[7] << 16);
    ((uint4*)wB)[g] = pk;
}

constexpr int CSTR = 40;
constexpr int SLAB = 3 * 66 * CSTR;

__global__ __launch_bounds__(256, 4) void gate_main_fb(
    const float* __restrict__ x, const float* __restrict__ bias,
    const unsigned short* __restrict__ wB, float* __restrict__ out) {
    __shared__ unsigned short xs[2 * SLAB];
    __shared__ float bias_s[64];
    __shared__ int   hist[64];

    const int tid  = threadIdx.x;
    const int lane = tid & 63;
    const int rw   = tid >> 6;
    const int blk  = blockIdx.x;
    const int b    = blk & 15;
    const int r    = blk >> 4;

    if (tid < 64) { bias_s[tid] = bias[tid]; hist[tid] = 0; }
    {
        uint4 z = {0u, 0u, 0u, 0u};
        uint4* p = (uint4*)xs;
#pragma unroll
        for (int i = 0; i < 8; ++i) {
            int idx = tid + i * 256;
            if (idx < 2 * SLAB / 8) p[idx] = z;
        }
    }

    bool tOk[4];
    int  tSrc[4], tDst[4];
#pragma unroll
    for (int i = 0; i < 4; ++i) {
        int T = tid + i * 256;
        bool ex = (T < 792);
        int chh = T / 198, s = T - chh * 198;
        int row2 = s / 66, wp = s - row2 * 66;
        int gr = r - 1 + row2, gwc = wp - 1;
        tOk[i]  = ex && (gr >= 0) && (gr < 64) && (gwc >= 0) && (gwc < 64);
        tSrc[i] = ((b * 256 + chh * 8) * 64 + gr) * 64 + gwc;
        tDst[i] = (row2 * 66 + wp) * CSTR + chh * 8;
    }

    float tb[4][8];
    auto issueT = [&](int i, int dq) {
        if (tOk[i]) {
            const float* p = x + tSrc[i] + dq * 131072;
#pragma unroll
            for (int u = 0; u < 8; ++u) tb[i][u] = p[u * 4096];
        }
    };
    auto commitT = [&](int i, unsigned short* dst) {
        if (tOk[i]) {
            uint4 pk;
            pk.x = (unsigned)f2h_bits(tb[i][0]) | ((unsigned)f2h_bits(tb[i][1]) << 16);
            pk.y = (unsigned)f2h_bits(tb[i][2]) | ((unsigned)f2h_bits(tb[i][3]) << 16);
            pk.z = (unsigned)f2h_bits(tb[i][4]) | ((unsigned)f2h_bits(tb[i][5]) << 16);
            pk.w = (unsigned)f2h_bits(tb[i][6]) | ((unsigned)f2h_bits(tb[i][7]) << 16);
            *(uint4*)(dst + tDst[i]) = pk;
        }
    };

    const int ph = rw >> 1, eh = rw & 1;
    half8 Aa[3][2];
    uint4 Bb[3][2];
    auto prefA = [&](const unsigned short* buf, int t, int slot) {
        const int kh = t / 3, kw = t % 3;
        const unsigned short* abase =
            buf + (kh * 66 + ph * 32 + (lane & 15) + kw) * CSTR + (lane >> 4) * 8;
#pragma unroll
        for (int mt = 0; mt < 2; ++mt)
            Aa[slot][mt] = *(const half8*)(abase + mt * 16 * CSTR);
    };
    auto prefB = [&](int T9, int slot) {
        const uint4* bp = (const uint4*)wB + (T9 * 4 + eh * 2) * 64 + lane;
#pragma unroll
        for (int nt = 0; nt < 2; ++nt) Bb[slot][nt] = bp[nt * 64];
    };

    f32x4 acc[2][2];
#pragma unroll
    for (int mt = 0; mt < 2; ++mt)
#pragma unroll
        for (int nt = 0; nt < 2; ++nt) acc[mt][nt] = (f32x4){0.f, 0.f, 0.f, 0.f};

    auto mfma_tap = [&](int slot) {
#pragma unroll
        for (int nt = 0; nt < 2; ++nt) {
            half8 bfr;
            __builtin_memcpy(&bfr, &Bb[slot][nt], 16);
#pragma unroll
            for (int mt = 0; mt < 2; ++mt)
                acc[mt][nt] = __builtin_amdgcn_mfma_f32_16x16x32_f16(
                    Aa[slot][mt], bfr, acc[mt][nt], 0, 0, 0);
        }
    };

    __syncthreads();
    issueT(0, 0); issueT(1, 0); issueT(2, 0); issueT(3, 0);
    commitT(0, xs); commitT(1, xs); commitT(2, xs); commitT(3, xs);
    issueT(0, 1); issueT(1, 1); issueT(2, 1); issueT(3, 1);
    prefB(0, 0); prefB(1, 1); prefB(2, 2);
    __syncthreads();

#pragma unroll 1
    for (int q = 0; q < 8; ++q) {
        const unsigned short* cur = xs + (q & 1) * SLAB;
        unsigned short*       nxt = xs + ((q + 1) & 1) * SLAB;
        const int  T0  = q * 9;
        const bool cmt = (q < 7);
        const bool iss = (q < 6);

        prefA(cur, 0, 0); prefA(cur, 1, 1);
        mfma_tap(0); prefB(T0 + 3, 0); prefA(cur, 2, 2);
        mfma_tap(1); prefB(T0 + 4, 1); prefA(cur, 3, 0);
        if (cmt) { commitT(0, nxt); commitT(1, nxt); }
        mfma_tap(2); prefB(T0 + 5, 2); prefA(cur, 4, 1);
        mfma_tap(0); prefB(T0 + 6, 0); prefA(cur, 5, 2);
        if (cmt) { commitT(2, nxt); commitT(3, nxt); }
        mfma_tap(1); prefB(T0 + 7, 1); prefA(cur, 6, 0);
        mfma_tap(2); prefB(T0 + 8, 2); prefA(cur, 7, 1);
        __builtin_amdgcn_sched_barrier(0);
        if (iss) { issueT(0, q + 2); issueT(1, q + 2); issueT(2, q + 2); issueT(3, q + 2); }
        __builtin_amdgcn_sched_barrier(0);
        mfma_tap(0); if (cmt) prefB(T0 + 9, 0);  prefA(cur, 8, 2);
        mfma_tap(1); if (cmt) prefB(T0 + 10, 1);
        mfma_tap(2); if (cmt) prefB(T0 + 11, 2);
        __syncthreads();
    }

    float* scf2 = (float*)xs;
#pragma unroll
    for (int mt = 0; mt < 2; ++mt)
#pragma unroll
        for (int nt = 0; nt < 2; ++nt)
#pragma unroll
            for (int rr = 0; rr < 4; ++rr) {
                float v = acc[mt][nt][rr];
                float s = 1.f / (1.f + __builtin_amdgcn_exp2f(-v * LOG2E));
                int p = ph * 32 + mt * 16 + ((lane >> 4) << 2) + rr;
                int e = eh * 32 + nt * 16 + (lane & 15);
                scf2[p * SSTR + e] = s;
            }
    __syncthreads();

    if (tid < 64) {
        const float* row = scf2 + tid * SSTR;
        float tv[8];
        int   ti[8];
#pragma unroll
        for (int k = 0; k < 8; ++k) { tv[k] = -3.0e38f; ti[k] = 0; }
#pragma unroll
        for (int j4 = 0; j4 < 16; ++j4) {
            f32x4 blkv = *(const f32x4*)(row + j4 * 4);
#pragma unroll
            for (int j = 0; j < 4; ++j) {
                int   e  = j4 * 4 + j;
                float bs = blkv[j] + bias_s[e];
                if (bs > tv[7]) {
                    tv[7] = bs; ti[7] = e;
#pragma unroll
                    for (int k = 7; k > 0; --k) {
                        float fa = tv[k - 1], fb = tv[k];
                        int   ia = ti[k - 1], ib = ti[k];
                        bool  sw = fb > fa;
                        tv[k - 1] = sw ? fb : fa; tv[k] = sw ? fa : fb;
                        ti[k - 1] = sw ? ib : ia; ti[k] = sw ? ia : ib;
                    }
                }
            }
        }
        float u[8], mx = -3.0e38f;
#pragma unroll
        for (int k = 0; k < 8; ++k) { u[k] = tv[k] - bias_s[ti[k]]; mx = fmaxf(mx, u[k]); }
        float ex[8], sum = 0.f;
#pragma unroll
        for (int k = 0; k < 8; ++k) { ex[k] = __builtin_amdgcn_exp2f((u[k] - mx) * LOG2E); sum += ex[k]; }
        float inv = 1.f / sum;

        int obase = b * 32768 + r * 64 + tid;
#pragma unroll
        for (int k = 0; k < 8; ++k) {
            out[obase + k * 4096]          = ex[k] * inv;
            out[524288 + obase + k * 4096] = (float)ti[k];
            atomicAdd(&hist[ti[k]], 1);
        }
    }
    __syncthreads();
    if (tid < 64) atomicAdd(out + 1048576 + tid, (float)hist[tid]);
}

// ---------------------------------------------------------------------------
extern "C" void kernel_launch(void* const* d_in, const int* in_sizes, int n_in,
                              void* d_out, int out_size, void* d_ws, size_t ws_size,
                              hipStream_t stream) {
    const float* x    = (const float*)d_in[0];
    const float* gw   = (const float*)d_in[1];
    const float* bias = (const float*)d_in[2];
    float* out = (float*)d_out;

    if (ws_size >= WS_NEED) {
        _Float16* xT = (_Float16*)d_ws;
        unsigned short* wB = (unsigned short*)((char*)d_ws + XT_BYTES);
        prep_all2<<<PREP_GRID, 256, 0, stream>>>(x, gw, xT, wB, out);
        gate_main3<<<1024, 256, 0, stream>>>(xT, bias, wB, out);
    } else {
        unsigned short* wB = (unsigned short*)d_ws;
        gate_prep<<<72, 256, 0, stream>>>(gw, wB, out);
        gate_main_fb<<<1024, 256, 0, stream>>>(x, bias, wB, out);
    }
}

// Round 5
// 172.639 us; speedup vs baseline: 1.3140x; 1.1286x over previous
//
#include <hip/hip_runtime.h>

// ---------------------------------------------------------------------------
// Gate_16501264351574: conv3x3(256ch -> 64 experts) + sigmoid + top8 + softmax
//   x: [16,256,64,64] f32, gate_w: [64,256,3,3] f32, bias: [64] f32
// out (flat f32): weights [16,8,64,64] | indices-as-f32 [16,8,64,64] | counts[64]
//
// R13: force the software pipeline. R12's VGPR_Count=36 proved LLVM sank
// every lda/ldb next to its consumer (source holds ~110 regs of slots),
// serializing each tap-group on a full L1/L2 round-trip -> MfmaUtil 7.9%.
// Fix: __builtin_amdgcn_sched_barrier(0) at every tap-group boundary.
// Loads issued for groups g+3 (A) / g+6 (B) can no longer sink; live
// ranges are forced; compiler's auto-waits become counted vmcnt (~10)
// instead of adjacent full drains. Everything else identical to R12:
//   xT2 [b][66row][8q][66w][32c] f16 (A-loads 1KB contiguous/wave),
//   barrier-free K loop, A slots 3-deep, B slots 6-deep, 1024 blocks,
//   4 blocks/CU.
// Fallback (ws too small): R9 structure verbatim.
// ---------------------------------------------------------------------------

typedef _Float16 half8 __attribute__((ext_vector_type(8)));
typedef __attribute__((ext_vector_type(4))) float f32x4;

#define LOG2E 1.44269504f

__device__ __forceinline__ unsigned short f2h_bits(float f) {
    _Float16 h = (_Float16)f;                  // v_cvt_f16_f32, RNE
    unsigned short b;
    __builtin_memcpy(&b, &h, 2);
    return b;
}

constexpr int WB_U4 = 8 * 9 * 4 * 64;          // 18432 uint4 = 294912 B
constexpr size_t XT_BYTES = (size_t)16 * 66 * 8 * 66 * 32 * 2;  // 35,684,352
constexpr size_t WS_NEED  = XT_BYTES + (size_t)WB_U4 * 16 + 262144;

// ===========================================================================
// FAST PATH
// ===========================================================================

// prep_all2 roles by blockIdx: [0,4096) interior transpose+cvt,
// [4096,4226) border zero, [4226,4298) wB fragments (+counts zero).
constexpr int NB_INT = 4096, NB_BOR = 130, NB_WB = 72;
constexpr int PREP_GRID = NB_INT + NB_BOR + NB_WB;   // 4298

__global__ __launch_bounds__(256) void prep_all2(
    const float* __restrict__ x, const float* __restrict__ gw,
    _Float16* __restrict__ xT, unsigned short* __restrict__ wB,
    float* __restrict__ out) {
    const int blk = blockIdx.x, tid = threadIdx.x;
    if (blk < NB_INT) {
        // interior: thread = (b, h, c16, w); reads coalesced along w.
        int gid = blk * 256 + tid;
        int w = gid & 63, c16 = (gid >> 6) & 15, h = (gid >> 10) & 63, b = gid >> 16;
        int c0 = c16 * 16;
        const float* src = x + ((b * 256 + c0) * 64 + h) * 64 + w;
        float v[16];
#pragma unroll
        for (int j = 0; j < 16; ++j) v[j] = src[j * 4096];
        uint4 p0, p1;
        p0.x = (unsigned)f2h_bits(v[0])  | ((unsigned)f2h_bits(v[1])  << 16);
        p0.y = (unsigned)f2h_bits(v[2])  | ((unsigned)f2h_bits(v[3])  << 16);
        p0.z = (unsigned)f2h_bits(v[4])  | ((unsigned)f2h_bits(v[5])  << 16);
        p0.w = (unsigned)f2h_bits(v[6])  | ((unsigned)f2h_bits(v[7])  << 16);
        p1.x = (unsigned)f2h_bits(v[8])  | ((unsigned)f2h_bits(v[9])  << 16);
        p1.y = (unsigned)f2h_bits(v[10]) | ((unsigned)f2h_bits(v[11]) << 16);
        p1.z = (unsigned)f2h_bits(v[12]) | ((unsigned)f2h_bits(v[13]) << 16);
        p1.w = (unsigned)f2h_bits(v[14]) | ((unsigned)f2h_bits(v[15]) << 16);
        // xT2 index: (((b*66 + h+1)*8 + q)*66 + (w+1))*32 + (c16&1)*16
        int q = c16 >> 1;
        size_t idx = ((((size_t)b * 66 + h + 1) * 8 + q) * 66 + (w + 1)) * 32
                     + (c16 & 1) * 16;
        uint4* dst = (uint4*)(xT + idx);
        dst[0] = p0; dst[1] = p1;
    } else if (blk < NB_INT + NB_BOR) {
        // border zero: 4160 sites x 8 q-slices x 64B; thread zeroes 64B.
        int t = (blk - NB_INT) * 256 + tid;    // < 33280 exactly
        int q = t & 7, site = t >> 3;          // site < 4160
        int sb = site / 260, s = site - sb * 260;
        int hp, wp;
        if (s < 132) { hp = (s >= 66) ? 65 : 0; wp = (s >= 66) ? (s - 66) : s; }
        else         { int s2 = s - 132; hp = 1 + (s2 >> 1); wp = (s2 & 1) * 65; }
        uint4 z = {0u, 0u, 0u, 0u};
        size_t idx = ((((size_t)sb * 66 + hp) * 8 + q) * 66 + wp) * 32;
        uint4* dst = (uint4*)(xT + idx);
#pragma unroll
        for (int k = 0; k < 4; ++k) dst[k] = z;
    } else {
        // wB: chunk-major f16 B-fragments (same layout as before).
        int wblk = blk - (NB_INT + NB_BOR);
        if (wblk == 0 && tid < 64) out[1048576 + tid] = 0.f;
        int g = wblk * 256 + tid;              // < WB_U4 exactly
        int lane = g & 63;
        int nt   = (g >> 6) & 3;
        int rest = g >> 8;                     // q*9 + t
        int t = rest % 9, q = rest / 9;
        int e  = nt * 16 + (lane & 15);
        int c0 = q * 32 + (lane >> 4) * 8;
        unsigned short o[8];
#pragma unroll
        for (int j = 0; j < 8; ++j)
            o[j] = f2h_bits(gw[(e * 256 + c0 + j) * 9 + t]);
        uint4 pk;
        pk.x = (unsigned)o[0] | ((unsigned)o[1] << 16);
        pk.y = (unsigned)o[2] | ((unsigned)o[3] << 16);
        pk.z = (unsigned)o[4] | ((unsigned)o[5] << 16);
        pk.w = (unsigned)o[6] | ((unsigned)o[7] << 16);
        ((uint4*)wB)[g] = pk;
    }
}

// ---------------------------------------------------------------------------
// gate_main3: grid 1024, block = one (b=blk&15, r=blk>>4): 4 waves,
// wave = 32pos x 32exp (ph = rw>>1, eh = rw&1). Barrier-free K loop,
// A slots 3-deep / B slots 6-deep, 2-chunk-unrolled body, sched_barrier(0)
// at every tap-group boundary to hold the pipeline in the emitted code.
// ---------------------------------------------------------------------------
constexpr int SSTR = 68;                       // fp32 score row stride
constexpr int QSTR = 66 * 32;                  // f16 per (row, q-slice) = 2112

__global__ __launch_bounds__(256, 4) void gate_main3(
    const _Float16* __restrict__ xT, const float* __restrict__ bias,
    const unsigned short* __restrict__ wB, float* __restrict__ out) {
    __shared__ float scf[64 * SSTR];           // 17408 B
    __shared__ float bias_s[64];
    __shared__ int   hist[64];

    const int tid  = threadIdx.x;
    const int lane = tid & 63;
    const int rw   = tid >> 6;
    const int blk  = blockIdx.x;
    const int b    = blk & 15;
    const int r    = blk >> 4;                 // output row 0..63

    if (tid < 64) { bias_s[tid] = bias[tid]; hist[tid] = 0; }

    const int ph = rw >> 1, eh = rw & 1;

    // A pointers, one per kh. Fragment addr(m, kw, q) = pa[kh]
    //   + q*QSTR (pointer bump per chunk) + (m*16 + kw)*32 (imm <= 1152B).
    const _Float16* pa[3];
#pragma unroll
    for (int kh = 0; kh < 3; ++kh)
        pa[kh] = xT + ((((size_t)b * 66 + r + kh) * 8) * 66
                       + ph * 32 + (lane & 15)) * 32 + (lane >> 4) * 8;

    // B pointer: monotonic, +256 uint4 per tap.
    const uint4* bptr = (const uint4*)wB + eh * 128 + lane;

    half8 Aa[3][2];
    uint4 Bb[6][2];
    f32x4 acc[2][2];
#pragma unroll
    for (int mt = 0; mt < 2; ++mt)
#pragma unroll
        for (int nt = 0; nt < 2; ++nt) acc[mt][nt] = (f32x4){0.f, 0.f, 0.f, 0.f};

    auto lda = [&](int t, int slot) {          // t, slot literals at call sites
        const int kh = t / 3, kw = t % 3;
#pragma unroll
        for (int m = 0; m < 2; ++m)
            Aa[slot][m] = *(const half8*)(pa[kh] + (m * 16 + kw) * 32);
    };
    auto ldb = [&](int slot) {
#pragma unroll
        for (int nt = 0; nt < 2; ++nt) Bb[slot][nt] = bptr[nt * 64];
        bptr += 256;
    };
    auto mt_ = [&](int as, int bs) {
#pragma unroll
        for (int nt = 0; nt < 2; ++nt) {
            half8 bfr;
            __builtin_memcpy(&bfr, &Bb[bs][nt], 16);
#pragma unroll
            for (int m = 0; m < 2; ++m)
                acc[m][nt] = __builtin_amdgcn_mfma_f32_16x16x32_f16(
                    Aa[as][m], bfr, acc[m][nt], 0, 0, 0);
        }
    };
    auto bump = [&]() {
#pragma unroll
        for (int kh = 0; kh < 3; ++kh) pa[kh] += QSTR;
    };
    auto SB = []() { __builtin_amdgcn_sched_barrier(0); };

    // prologue: A taps 0..2 -> slots 0..2; B taps 0..5 -> slots 0..5.
    lda(0, 0); lda(1, 1); lda(2, 2);
    ldb(0); ldb(1); ldb(2); ldb(3); ldb(4); ldb(5);
    SB();

    // body: 4 iterations x 2 chunks (18 tap-groups). Group j consumes
    // global tap j (a-slot j%3, b-slot j%6), reloads a-slot with tap j+3,
    // b-slot with tap j+6 (bptr monotonic). sched_barrier(0) pins each
    // group so loads cannot sink to their consumers (R12's collapse).
#pragma unroll 1
    for (int i = 0; i < 4; ++i) {
        mt_(0, 0); lda(3, 0); ldb(0); SB();
        mt_(1, 1); lda(4, 1); ldb(1); SB();
        mt_(2, 2); lda(5, 2); ldb(2); SB();
        mt_(0, 3); lda(6, 0); ldb(3); SB();
        mt_(1, 4); lda(7, 1); ldb(4); SB();
        mt_(2, 5); lda(8, 2); ldb(5); SB();
        bump();                                // pa -> chunk c+1
        mt_(0, 0); lda(0, 0); ldb(0); SB();
        mt_(1, 1); lda(1, 1); ldb(1); SB();
        mt_(2, 2); lda(2, 2); ldb(2); SB();
        mt_(0, 3); lda(3, 0); ldb(3); SB();
        mt_(1, 4); lda(4, 1); ldb(4); SB();
        mt_(2, 5); lda(5, 2); ldb(5); SB();
        mt_(0, 0); lda(6, 0); ldb(0); SB();
        mt_(1, 1); lda(7, 1); ldb(1); SB();
        mt_(2, 2); lda(8, 2); ldb(2); SB();
        bump();                                // pa -> chunk c+2
        mt_(0, 3); lda(0, 0); ldb(3); SB();
        mt_(1, 4); lda(1, 1); ldb(4); SB();
        mt_(2, 5); lda(2, 2); ldb(5); SB();
        // final iter: trailing loads read chunk-8 / wB-tail garbage inside
        // the workspace slack (never consumed) -- safe by WS_NEED slack.
    }

    // ---- epilogue: sigmoid -> fp32 scores in LDS ---------------------------
#pragma unroll
    for (int mt = 0; mt < 2; ++mt)
#pragma unroll
        for (int nt = 0; nt < 2; ++nt)
#pragma unroll
            for (int rr = 0; rr < 4; ++rr) {
                float v = acc[mt][nt][rr];
                float s = 1.f / (1.f + __builtin_amdgcn_exp2f(-v * LOG2E));
                int p = ph * 32 + mt * 16 + ((lane >> 4) << 2) + rr;
                int e = eh * 32 + nt * 16 + (lane & 15);
                scf[p * SSTR + e] = s;
            }
    __syncthreads();

    if (tid < 64) {
        const float* row = scf + tid * SSTR;
        float tv[8];
        int   ti[8];
#pragma unroll
        for (int k = 0; k < 8; ++k) { tv[k] = -3.0e38f; ti[k] = 0; }
#pragma unroll
        for (int j4 = 0; j4 < 16; ++j4) {
            f32x4 blkv = *(const f32x4*)(row + j4 * 4);
#pragma unroll
            for (int j = 0; j < 4; ++j) {
                int   e  = j4 * 4 + j;
                float bs = blkv[j] + bias_s[e];
                if (bs > tv[7]) {
                    tv[7] = bs; ti[7] = e;
#pragma unroll
                    for (int k = 7; k > 0; --k) {
                        float fa = tv[k - 1], fb = tv[k];
                        int   ia = ti[k - 1], ib = ti[k];
                        bool  sw = fb > fa;
                        tv[k - 1] = sw ? fb : fa; tv[k] = sw ? fa : fb;
                        ti[k - 1] = sw ? ib : ia; ti[k] = sw ? ia : ib;
                    }
                }
            }
        }
        float u[8], mx = -3.0e38f;
#pragma unroll
        for (int k = 0; k < 8; ++k) { u[k] = tv[k] - bias_s[ti[k]]; mx = fmaxf(mx, u[k]); }
        float ex[8], sum = 0.f;
#pragma unroll
        for (int k = 0; k < 8; ++k) { ex[k] = __builtin_amdgcn_exp2f((u[k] - mx) * LOG2E); sum += ex[k]; }
        float inv = 1.f / sum;

        int obase = b * 32768 + r * 64 + tid;
#pragma unroll
        for (int k = 0; k < 8; ++k) {
            out[obase + k * 4096]          = ex[k] * inv;
            out[524288 + obase + k * 4096] = (float)ti[k];
            atomicAdd(&hist[ti[k]], 1);
        }
    }
    __syncthreads();
    if (tid < 64) atomicAdd(out + 1048576 + tid, (float)hist[tid]);
}

// ===========================================================================
// FALLBACK PATH (R9 verbatim: best measured, gate_main ~78 us)
// ===========================================================================

__global__ __launch_bounds__(256) void gate_prep(const float* __restrict__ gw,
                                                 unsigned short* __restrict__ wB,
                                                 float* __restrict__ out) {
    int g = blockIdx.x * 256 + threadIdx.x;
    if (blockIdx.x == 0 && threadIdx.x < 64) out[1048576 + threadIdx.x] = 0.f;
    if (g >= WB_U4) return;
    int lane = g & 63;
    int nt   = (g >> 6) & 3;
    int rest = g >> 8;
    int t = rest % 9, q = rest / 9;
    int e  = nt * 16 + (lane & 15);
    int c0 = q * 32 + (lane >> 4) * 8;
    unsigned short o[8];
#pragma unroll
    for (int j = 0; j < 8; ++j)
        o[j] = f2h_bits(gw[(e * 256 + c0 + j) * 9 + t]);
    uint4 pk;
    pk.x = (unsigned)o[0] | ((unsigned)o[1] << 16);
    pk.y = (unsigned)o[2] | ((unsigned)o[3] << 16);
    pk.z = (unsigned)o[4] | ((unsigned)o[5] << 16);
    pk.w = (unsigned)o[6] | ((unsigned)o[7] << 16);
    ((uint4*)wB)[g] = pk;
}

constexpr int CSTR = 40;
constexpr int SLAB = 3 * 66 * CSTR;

__global__ __launch_bounds__(256, 4) void gate_main_fb(
    const float* __restrict__ x, const float* __restrict__ bias,
    const unsigned short* __restrict__ wB, float* __restrict__ out) {
    __shared__ unsigned short xs[2 * SLAB];
    __shared__ float bias_s[64];
    __shared__ int   hist[64];

    const int tid  = threadIdx.x;
    const int lane = tid & 63;
    const int rw   = tid >> 6;
    const int blk  = blockIdx.x;
    const int b    = blk & 15;
    const int r    = blk >> 4;

    if (tid < 64) { bias_s[tid] = bias[tid]; hist[tid] = 0; }
    {
        uint4 z = {0u, 0u, 0u, 0u};
        uint4* p = (uint4*)xs;
#pragma unroll
        for (int i = 0; i < 8; ++i) {
            int idx = tid + i * 256;
            if (idx < 2 * SLAB / 8) p[idx] = z;
        }
    }

    bool tOk[4];
    int  tSrc[4], tDst[4];
#pragma unroll
    for (int i = 0; i < 4; ++i) {
        int T = tid + i * 256;
        bool ex = (T < 792);
        int chh = T / 198, s = T - chh * 198;
        int row2 = s / 66, wp = s - row2 * 66;
        int gr = r - 1 + row2, gwc = wp - 1;
        tOk[i]  = ex && (gr >= 0) && (gr < 64) && (gwc >= 0) && (gwc < 64);
        tSrc[i] = ((b * 256 + chh * 8) * 64 + gr) * 64 + gwc;
        tDst[i] = (row2 * 66 + wp) * CSTR + chh * 8;
    }

    float tb[4][8];
    auto issueT = [&](int i, int dq) {
        if (tOk[i]) {
            const float* p = x + tSrc[i] + dq * 131072;
#pragma unroll
            for (int u = 0; u < 8; ++u) tb[i][u] = p[u * 4096];
        }
    };
    auto commitT = [&](int i, unsigned short* dst) {
        if (tOk[i]) {
            uint4 pk;
            pk.x = (unsigned)f2h_bits(tb[i][0]) | ((unsigned)f2h_bits(tb[i][1]) << 16);
            pk.y = (unsigned)f2h_bits(tb[i][2]) | ((unsigned)f2h_bits(tb[i][3]) << 16);
            pk.z = (unsigned)f2h_bits(tb[i][4]) | ((unsigned)f2h_bits(tb[i][5]) << 16);
            pk.w = (unsigned)f2h_bits(tb[i][6]) | ((unsigned)f2h_bits(tb[i][7]) << 16);
            *(uint4*)(dst + tDst[i]) = pk;
        }
    };

    const int ph = rw >> 1, eh = rw & 1;
    half8 Aa[3][2];
    uint4 Bb[3][2];
    auto prefA = [&](const unsigned short* buf, int t, int slot) {
        const int kh = t / 3, kw = t % 3;
        const unsigned short* abase =
            buf + (kh * 66 + ph * 32 + (lane & 15) + kw) * CSTR + (lane >> 4) * 8;
#pragma unroll
        for (int mt = 0; mt < 2; ++mt)
            Aa[slot][mt] = *(const half8*)(abase + mt * 16 * CSTR);
    };
    auto prefB = [&](int T9, int slot) {
        const uint4* bp = (const uint4*)wB + (T9 * 4 + eh * 2) * 64 + lane;
#pragma unroll
        for (int nt = 0; nt < 2; ++nt) Bb[slot][nt] = bp[nt * 64];
    };

    f32x4 acc[2][2];
#pragma unroll
    for (int mt = 0; mt < 2; ++mt)
#pragma unroll
        for (int nt = 0; nt < 2; ++nt) acc[mt][nt] = (f32x4){0.f, 0.f, 0.f, 0.f};

    auto mfma_tap = [&](int slot) {
#pragma unroll
        for (int nt = 0; nt < 2; ++nt) {
            half8 bfr;
            __builtin_memcpy(&bfr, &Bb[slot][nt], 16);
#pragma unroll
            for (int mt = 0; mt < 2; ++mt)
                acc[mt][nt] = __builtin_amdgcn_mfma_f32_16x16x32_f16(
                    Aa[slot][mt], bfr, acc[mt][nt], 0, 0, 0);
        }
    };

    __syncthreads();
    issueT(0, 0); issueT(1, 0); issueT(2, 0); issueT(3, 0);
    commitT(0, xs); commitT(1, xs); commitT(2, xs); commitT(3, xs);
    issueT(0, 1); issueT(1, 1); issueT(2, 1); issueT(3, 1);
    prefB(0, 0); prefB(1, 1); prefB(2, 2);
    __syncthreads();

#pragma unroll 1
    for (int q = 0; q < 8; ++q) {
        const unsigned short* cur = xs + (q & 1) * SLAB;
        unsigned short*       nxt = xs + ((q + 1) & 1) * SLAB;
        const int  T0  = q * 9;
        const bool cmt = (q < 7);
        const bool iss = (q < 6);

        prefA(cur, 0, 0); prefA(cur, 1, 1);
        mfma_tap(0); prefB(T0 + 3, 0); prefA(cur, 2, 2);
        mfma_tap(1); prefB(T0 + 4, 1); prefA(cur, 3, 0);
        if (cmt) { commitT(0, nxt); commitT(1, nxt); }
        mfma_tap(2); prefB(T0 + 5, 2); prefA(cur, 4, 1);
        mfma_tap(0); prefB(T0 + 6, 0); prefA(cur, 5, 2);
        if (cmt) { commitT(2, nxt); commitT(3, nxt); }
        mfma_tap(1); prefB(T0 + 7, 1); prefA(cur, 6, 0);
        mfma_tap(2); prefB(T0 + 8, 2); prefA(cur, 7, 1);
        __builtin_amdgcn_sched_barrier(0);
        if (iss) { issueT(0, q + 2); issueT(1, q + 2); issueT(2, q + 2); issueT(3, q + 2); }
        __builtin_amdgcn_sched_barrier(0);
        mfma_tap(0); if (cmt) prefB(T0 + 9, 0);  prefA(cur, 8, 2);
        mfma_tap(1); if (cmt) prefB(T0 + 10, 1);
        mfma_tap(2); if (cmt) prefB(T0 + 11, 2);
        __syncthreads();
    }

    float* scf2 = (float*)xs;
#pragma unroll
    for (int mt = 0; mt < 2; ++mt)
#pragma unroll
        for (int nt = 0; nt < 2; ++nt)
#pragma unroll
            for (int rr = 0; rr < 4; ++rr) {
                float v = acc[mt][nt][rr];
                float s = 1.f / (1.f + __builtin_amdgcn_exp2f(-v * LOG2E));
                int p = ph * 32 + mt * 16 + ((lane >> 4) << 2) + rr;
                int e = eh * 32 + nt * 16 + (lane & 15);
                scf2[p * SSTR + e] = s;
            }
    __syncthreads();

    if (tid < 64) {
        const float* row = scf2 + tid * SSTR;
        float tv[8];
        int   ti[8];
#pragma unroll
        for (int k = 0; k < 8; ++k) { tv[k] = -3.0e38f; ti[k] = 0; }
#pragma unroll
        for (int j4 = 0; j4 < 16; ++j4) {
            f32x4 blkv = *(const f32x4*)(row + j4 * 4);
#pragma unroll
            for (int j = 0; j < 4; ++j) {
                int   e  = j4 * 4 + j;
                float bs = blkv[j] + bias_s[e];
                if (bs > tv[7]) {
                    tv[7] = bs; ti[7] = e;
#pragma unroll
                    for (int k = 7; k > 0; --k) {
                        float fa = tv[k - 1], fb = tv[k];
                        int   ia = ti[k - 1], ib = ti[k];
                        bool  sw = fb > fa;
                        tv[k - 1] = sw ? fb : fa; tv[k] = sw ? fa : fb;
                        ti[k - 1] = sw ? ib : ia; ti[k] = sw ? ia : ib;
                    }
                }
            }
        }
        float u[8], mx = -3.0e38f;
#pragma unroll
        for (int k = 0; k < 8; ++k) { u[k] = tv[k] - bias_s[ti[k]]; mx = fmaxf(mx, u[k]); }
        float ex[8], sum = 0.f;
#pragma unroll
        for (int k = 0; k < 8; ++k) { ex[k] = __builtin_amdgcn_exp2f((u[k] - mx) * LOG2E); sum += ex[k]; }
        float inv = 1.f / sum;

        int obase = b * 32768 + r * 64 + tid;
#pragma unroll
        for (int k = 0; k < 8; ++k) {
            out[obase + k * 4096]          = ex[k] * inv;
            out[524288 + obase + k * 4096] = (float)ti[k];
            atomicAdd(&hist[ti[k]], 1);
        }
    }
    __syncthreads();
    if (tid < 64) atomicAdd(out + 1048576 + tid, (float)hist[tid]);
}

// ---------------------------------------------------------------------------
extern "C" void kernel_launch(void* const* d_in, const int* in_sizes, int n_in,
                              void* d_out, int out_size, void* d_ws, size_t ws_size,
                              hipStream_t stream) {
    const float* x    = (const float*)d_in[0];
    const float* gw   = (const float*)d_in[1];
    const float* bias = (const float*)d_in[2];
    float* out = (float*)d_out;

    if (ws_size >= WS_NEED) {
        _Float16* xT = (_Float16*)d_ws;
        unsigned short* wB = (unsigned short*)((char*)d_ws + XT_BYTES);
        prep_all2<<<PREP_GRID, 256, 0, stream>>>(x, gw, xT, wB, out);
        gate_main3<<<1024, 256, 0, stream>>>(xT, bias, wB, out);
    } else {
        unsigned short* wB = (unsigned short*)d_ws;
        gate_prep<<<72, 256, 0, stream>>>(gw, wB, out);
        gate_main_fb<<<1024, 256, 0, stream>>>(x, bias, wB, out);
    }
}

// Round 6
// 154.997 us; speedup vs baseline: 1.4635x; 1.1138x over previous
//
#include <hip/hip_runtime.h>

// ---------------------------------------------------------------------------
// Gate_16501264351574: conv3x3(256ch -> 64 experts) + sigmoid + top8 + softmax
//   x: [16,256,64,64] f32, gate_w: [64,256,3,3] f32, bias: [64] f32
// out (flat f32): weights [16,8,64,64] | indices-as-f32 [16,8,64,64] | counts[64]
//
// R14: split A and B across the two wait counters. R11-R13 proved direct-
// global A+B cannot pipeline: one in-order vmcnt stream means every A
// consume retires behind older L2-latency B loads (~600cy/group, MfmaUtil
// 10%, VGPR 64 = scheduler collapsed the slots). Now:
//   A: global_load_lds from xT2 into a double-buffered LDS slab (12,672B
//      per chunk = 3 contiguous 4,224B segments; linear dest, 16B/lane, no
//      VALU cvt). Consumed as ds_read_b128 (base VGPR + imm offsets, 64B
//      lane stride -> uniform banks). A waits = lgkmcnt, decoupled from B.
//   B: monotonic 6-deep register rotation (slot = G%6, static via 2-chunk
//      unrolled body), exactly as R12/R13.
//   Chunk barrier = m201 idiom: s_waitcnt vmcnt(18) lgkmcnt(0) + raw
//      s_barrier. 18 = B-loads issued after the staging batch -> staging
//      proven landed, B stays in flight (fixes R10's mistake).
// Fallback (ws too small): R9 structure verbatim.
// ---------------------------------------------------------------------------

typedef _Float16 half8 __attribute__((ext_vector_type(8)));
typedef __attribute__((ext_vector_type(4))) float f32x4;

#define LOG2E 1.44269504f

__device__ __forceinline__ unsigned short f2h_bits(float f) {
    _Float16 h = (_Float16)f;                  // v_cvt_f16_f32, RNE
    unsigned short b;
    __builtin_memcpy(&b, &h, 2);
    return b;
}

constexpr int WB_U4 = 8 * 9 * 4 * 64;          // 18432 uint4 = 294912 B
constexpr size_t XT_BYTES = (size_t)16 * 66 * 8 * 66 * 32 * 2;  // 35,684,352
constexpr size_t WS_NEED  = XT_BYTES + (size_t)WB_U4 * 16 + 262144;

#define GLOAD16(gp, lp)                                                    \
    __builtin_amdgcn_global_load_lds(                                      \
        (const __attribute__((address_space(1))) void*)(gp),               \
        (__attribute__((address_space(3))) void*)(lp), 16, 0, 0)

// ===========================================================================
// FAST PATH
// ===========================================================================

// prep_all2 roles by blockIdx: [0,4096) interior transpose+cvt,
// [4096,4226) border zero, [4226,4298) wB fragments (+counts zero).
constexpr int NB_INT = 4096, NB_BOR = 130, NB_WB = 72;
constexpr int PREP_GRID = NB_INT + NB_BOR + NB_WB;   // 4298

__global__ __launch_bounds__(256) void prep_all2(
    const float* __restrict__ x, const float* __restrict__ gw,
    _Float16* __restrict__ xT, unsigned short* __restrict__ wB,
    float* __restrict__ out) {
    const int blk = blockIdx.x, tid = threadIdx.x;
    if (blk < NB_INT) {
        // interior: thread = (b, h, c16, w); reads coalesced along w.
        int gid = blk * 256 + tid;
        int w = gid & 63, c16 = (gid >> 6) & 15, h = (gid >> 10) & 63, b = gid >> 16;
        int c0 = c16 * 16;
        const float* src = x + ((b * 256 + c0) * 64 + h) * 64 + w;
        float v[16];
#pragma unroll
        for (int j = 0; j < 16; ++j) v[j] = src[j * 4096];
        uint4 p0, p1;
        p0.x = (unsigned)f2h_bits(v[0])  | ((unsigned)f2h_bits(v[1])  << 16);
        p0.y = (unsigned)f2h_bits(v[2])  | ((unsigned)f2h_bits(v[3])  << 16);
        p0.z = (unsigned)f2h_bits(v[4])  | ((unsigned)f2h_bits(v[5])  << 16);
        p0.w = (unsigned)f2h_bits(v[6])  | ((unsigned)f2h_bits(v[7])  << 16);
        p1.x = (unsigned)f2h_bits(v[8])  | ((unsigned)f2h_bits(v[9])  << 16);
        p1.y = (unsigned)f2h_bits(v[10]) | ((unsigned)f2h_bits(v[11]) << 16);
        p1.z = (unsigned)f2h_bits(v[12]) | ((unsigned)f2h_bits(v[13]) << 16);
        p1.w = (unsigned)f2h_bits(v[14]) | ((unsigned)f2h_bits(v[15]) << 16);
        int q = c16 >> 1;
        size_t idx = ((((size_t)b * 66 + h + 1) * 8 + q) * 66 + (w + 1)) * 32
                     + (c16 & 1) * 16;
        uint4* dst = (uint4*)(xT + idx);
        dst[0] = p0; dst[1] = p1;
    } else if (blk < NB_INT + NB_BOR) {
        // border zero: 4160 sites x 8 q-slices x 64B; thread zeroes 64B.
        int t = (blk - NB_INT) * 256 + tid;    // < 33280 exactly
        int q = t & 7, site = t >> 3;          // site < 4160
        int sb = site / 260, s = site - sb * 260;
        int hp, wp;
        if (s < 132) { hp = (s >= 66) ? 65 : 0; wp = (s >= 66) ? (s - 66) : s; }
        else         { int s2 = s - 132; hp = 1 + (s2 >> 1); wp = (s2 & 1) * 65; }
        uint4 z = {0u, 0u, 0u, 0u};
        size_t idx = ((((size_t)sb * 66 + hp) * 8 + q) * 66 + wp) * 32;
        uint4* dst = (uint4*)(xT + idx);
#pragma unroll
        for (int k = 0; k < 4; ++k) dst[k] = z;
    } else {
        // wB: chunk-major f16 B-fragments.
        int wblk = blk - (NB_INT + NB_BOR);
        if (wblk == 0 && tid < 64) out[1048576 + tid] = 0.f;
        int g = wblk * 256 + tid;              // < WB_U4 exactly
        int lane = g & 63;
        int nt   = (g >> 6) & 3;
        int rest = g >> 8;                     // q*9 + t
        int t = rest % 9, q = rest / 9;
        int e  = nt * 16 + (lane & 15);
        int c0 = q * 32 + (lane >> 4) * 8;
        unsigned short o[8];
#pragma unroll
        for (int j = 0; j < 8; ++j)
            o[j] = f2h_bits(gw[(e * 256 + c0 + j) * 9 + t]);
        uint4 pk;
        pk.x = (unsigned)o[0] | ((unsigned)o[1] << 16);
        pk.y = (unsigned)o[2] | ((unsigned)o[3] << 16);
        pk.z = (unsigned)o[4] | ((unsigned)o[5] << 16);
        pk.w = (unsigned)o[6] | ((unsigned)o[7] << 16);
        ((uint4*)wB)[g] = pk;
    }
}

// ---------------------------------------------------------------------------
// gate_main4: grid 1024, block = (b=blk&15, r=blk>>4), 4 waves,
// wave = 32pos x 32exp (ph = rw>>1, eh = rw&1).
// LDS: slab dbuf 2 x 12672 B (A chunks); scf epilogue aliases slab.
// ---------------------------------------------------------------------------
constexpr int SSTR = 68;                       // fp32 score row stride
constexpr int HALFB = 12672;                   // slab half size (bytes)

__global__ __launch_bounds__(256, 4) void gate_main4(
    const _Float16* __restrict__ xT, const float* __restrict__ bias,
    const unsigned short* __restrict__ wB, float* __restrict__ out) {
    __shared__ uint4 smem4[2 * HALFB / 16];    // 25344 B (scf aliases)
    __shared__ float bias_s[64];
    __shared__ int   hist[64];
    char* smem = (char*)smem4;

    const int tid  = threadIdx.x;
    const int lane = tid & 63;
    const int rw   = tid >> 6;
    const int blk  = blockIdx.x;
    const int b    = blk & 15;
    const int r    = blk >> 4;                 // output row 0..63

    if (tid < 64) { bias_s[tid] = bias[tid]; hist[tid] = 0; }

    const int ph = rw >> 1, eh = rw & 1;

    // ---- staging task descriptors: 792 granules = 3 segs x 264 x 16B ------
    // T = tid + i*256; i<3 always active; i==3 only tid<24.
    const _Float16* srcP[4];
    int ldsOff[4];
    const bool act3 = (tid < 24);
#pragma unroll
    for (int i = 0; i < 4; ++i) {
        int T = tid + i * 256;
        if (T >= 792) T = 0;                   // inactive (i==3, tid>=24)
        int seg = T / 264, o = T - seg * 264;
        srcP[i]  = xT + ((size_t)(b * 66 + r + seg) * 8) * 2112 + o * 8;
        ldsOff[i] = T * 16;
    }
    auto STAGE = [&](int q, int halfB) {       // 3-4 global_load_lds, 16B each
#pragma unroll
        for (int i = 0; i < 3; ++i)
            GLOAD16(srcP[i] + q * 2112, smem + ldsOff[i] + halfB);
        if (act3)
            GLOAD16(srcP[3] + q * 2112, smem + ldsOff[3] + halfB);
    };

    // ---- A reads: ds_read_b128, one base VGPR + immediate offsets ---------
    // slab layout [kh(3)][w(66)][c8(4)] x 16B; lane: w += lane&15, c8 = lane>>4.
    const char* aP0 = smem + ((ph * 32 + (lane & 15)) * 64 + (lane >> 4) * 16);
    half8 Aa[3][2];
    uint4 Bb[6][2];
    f32x4 acc[2][2];
#pragma unroll
    for (int mt = 0; mt < 2; ++mt)
#pragma unroll
        for (int nt = 0; nt < 2; ++nt) acc[mt][nt] = (f32x4){0.f, 0.f, 0.f, 0.f};

    auto LDA = [&](int kh, int kw, int slot, int HB) {   // all args literal
        Aa[slot][0] = *(const half8*)(aP0 + HB + kh * 4224 + kw * 64);
        Aa[slot][1] = *(const half8*)(aP0 + HB + kh * 4224 + kw * 64 + 1024);
    };
    // B: monotonic pointer, +4096B per tap (taps 0..77; 72..77 overread into
    // workspace slack, never consumed).
    const char* bP = (const char*)wB + eh * 2048 + lane * 16;
    auto LDB = [&](int slot) {
        Bb[slot][0] = *(const uint4*)bP;
        Bb[slot][1] = *(const uint4*)(bP + 1024);
        bP += 4096;
    };
    auto MT = [&](int as, int bs) {
#pragma unroll
        for (int nt = 0; nt < 2; ++nt) {
            half8 bfr;
            __builtin_memcpy(&bfr, &Bb[bs][nt], 16);
#pragma unroll
            for (int m = 0; m < 2; ++m)
                acc[m][nt] = __builtin_amdgcn_mfma_f32_16x16x32_f16(
                    Aa[as][m], bfr, acc[m][nt], 0, 0, 0);
        }
    };
    auto SB = []() { __builtin_amdgcn_sched_barrier(0); };

    // ---- prologue: stage chunk 0, prefetch B taps 0..5 --------------------
    STAGE(0, 0);
    LDB(0); LDB(1); LDB(2); LDB(3); LDB(4); LDB(5);
    SB();
    asm volatile("s_waitcnt vmcnt(12)" ::: "memory");   // staging(0) landed
    __builtin_amdgcn_s_barrier();
    SB();

    // ---- K loop: 4 x (2 chunks x 9 taps). Counted-vmcnt barrier per chunk.
#pragma unroll 1
    for (int i = 0; i < 4; ++i) {
        // ============ sub-chunk A (q = 2i, reads half 0) ==================
        STAGE(2 * i + 1, HALFB);
        LDA(0, 0, 0, 0); LDA(0, 1, 1, 0); LDA(0, 2, 2, 0);
        SB();
        MT(0, 0); LDA(1, 0, 0, 0); LDB(0); SB();
        MT(1, 1); LDA(1, 1, 1, 0); LDB(1); SB();
        MT(2, 2); LDA(1, 2, 2, 0); LDB(2); SB();
        MT(0, 3); LDA(2, 0, 0, 0); LDB(3); SB();
        MT(1, 4); LDA(2, 1, 1, 0); LDB(4); SB();
        MT(2, 5); LDA(2, 2, 2, 0); LDB(5); SB();
        MT(0, 0); LDB(0); SB();
        MT(1, 1); LDB(1); SB();
        MT(2, 2); LDB(2); SB();
        SB();
        asm volatile("s_waitcnt vmcnt(18) lgkmcnt(0)" ::: "memory");
        __builtin_amdgcn_s_barrier();
        SB();
        // ============ sub-chunk B (q = 2i+1, reads half HALFB) ============
        if (i < 3) STAGE(2 * i + 2, 0);
        LDA(0, 0, 0, HALFB); LDA(0, 1, 1, HALFB); LDA(0, 2, 2, HALFB);
        SB();
        MT(0, 3); LDA(1, 0, 0, HALFB); LDB(3); SB();
        MT(1, 4); LDA(1, 1, 1, HALFB); LDB(4); SB();
        MT(2, 5); LDA(1, 2, 2, HALFB); LDB(5); SB();
        MT(0, 0); LDA(2, 0, 0, HALFB); LDB(0); SB();
        MT(1, 1); LDA(2, 1, 1, HALFB); LDB(1); SB();
        MT(2, 2); LDA(2, 2, 2, HALFB); LDB(2); SB();
        MT(0, 3); LDB(3); SB();
        MT(1, 4); LDB(4); SB();
        MT(2, 5); LDB(5); SB();
        if (i < 3) {
            SB();
            asm volatile("s_waitcnt vmcnt(18) lgkmcnt(0)" ::: "memory");
            __builtin_amdgcn_s_barrier();
            SB();
        }
    }
    __syncthreads();                           // full drain before scf alias

    // ---- epilogue: sigmoid -> fp32 scores in LDS (aliases slab) -----------
    float* scf = (float*)smem4;                // [64][68] f32 = 17408 B
#pragma unroll
    for (int mt = 0; mt < 2; ++mt)
#pragma unroll
        for (int nt = 0; nt < 2; ++nt)
#pragma unroll
            for (int rr = 0; rr < 4; ++rr) {
                float v = acc[mt][nt][rr];
                float s = 1.f / (1.f + __builtin_amdgcn_exp2f(-v * LOG2E));
                int p = ph * 32 + mt * 16 + ((lane >> 4) << 2) + rr;
                int e = eh * 32 + nt * 16 + (lane & 15);
                scf[p * SSTR + e] = s;
            }
    __syncthreads();

    if (tid < 64) {
        const float* row = scf + tid * SSTR;
        float tv[8];
        int   ti[8];
#pragma unroll
        for (int k = 0; k < 8; ++k) { tv[k] = -3.0e38f; ti[k] = 0; }
#pragma unroll
        for (int j4 = 0; j4 < 16; ++j4) {
            f32x4 blkv = *(const f32x4*)(row + j4 * 4);
#pragma unroll
            for (int j = 0; j < 4; ++j) {
                int   e  = j4 * 4 + j;
                float bs = blkv[j] + bias_s[e];
                if (bs > tv[7]) {
                    tv[7] = bs; ti[7] = e;
#pragma unroll
                    for (int k = 7; k > 0; --k) {
                        float fa = tv[k - 1], fb = tv[k];
                        int   ia = ti[k - 1], ib = ti[k];
                        bool  sw = fb > fa;
                        tv[k - 1] = sw ? fb : fa; tv[k] = sw ? fa : fb;
                        ti[k - 1] = sw ? ib : ia; ti[k] = sw ? ia : ib;
                    }
                }
            }
        }
        float u[8], mx = -3.0e38f;
#pragma unroll
        for (int k = 0; k < 8; ++k) { u[k] = tv[k] - bias_s[ti[k]]; mx = fmaxf(mx, u[k]); }
        float ex[8], sum = 0.f;
#pragma unroll
        for (int k = 0; k < 8; ++k) { ex[k] = __builtin_amdgcn_exp2f((u[k] - mx) * LOG2E); sum += ex[k]; }
        float inv = 1.f / sum;

        int obase = b * 32768 + r * 64 + tid;
#pragma unroll
        for (int k = 0; k < 8; ++k) {
            out[obase + k * 4096]          = ex[k] * inv;
            out[524288 + obase + k * 4096] = (float)ti[k];
            atomicAdd(&hist[ti[k]], 1);
        }
    }
    __syncthreads();
    if (tid < 64) atomicAdd(out + 1048576 + tid, (float)hist[tid]);
}

// ===========================================================================
// FALLBACK PATH (R9 verbatim)
// ===========================================================================

__global__ __launch_bounds__(256) void gate_prep(const float* __restrict__ gw,
                                                 unsigned short* __restrict__ wB,
                                                 float* __restrict__ out) {
    int g = blockIdx.x * 256 + threadIdx.x;
    if (blockIdx.x == 0 && threadIdx.x < 64) out[1048576 + threadIdx.x] = 0.f;
    if (g >= WB_U4) return;
    int lane = g & 63;
    int nt   = (g >> 6) & 3;
    int rest = g >> 8;
    int t = rest % 9, q = rest / 9;
    int e  = nt * 16 + (lane & 15);
    int c0 = q * 32 + (lane >> 4) * 8;
    unsigned short o[8];
#pragma unroll
    for (int j = 0; j < 8; ++j)
        o[j] = f2h_bits(gw[(e * 256 + c0 + j) * 9 + t]);
    uint4 pk;
    pk.x = (unsigned)o[0] | ((unsigned)o[1] << 16);
    pk.y = (unsigned)o[2] | ((unsigned)o[3] << 16);
    pk.z = (unsigned)o[4] | ((unsigned)o[5] << 16);
    pk.w = (unsigned)o[6] | ((unsigned)o[7] << 16);
    ((uint4*)wB)[g] = pk;
}

constexpr int CSTR = 40;
constexpr int SLAB = 3 * 66 * CSTR;

__global__ __launch_bounds__(256, 4) void gate_main_fb(
    const float* __restrict__ x, const float* __restrict__ bias,
    const unsigned short* __restrict__ wB, float* __restrict__ out) {
    __shared__ unsigned short xs[2 * SLAB];
    __shared__ float bias_s[64];
    __shared__ int   hist[64];

    const int tid  = threadIdx.x;
    const int lane = tid & 63;
    const int rw   = tid >> 6;
    const int blk  = blockIdx.x;
    const int b    = blk & 15;
    const int r    = blk >> 4;

    if (tid < 64) { bias_s[tid] = bias[tid]; hist[tid] = 0; }
    {
        uint4 z = {0u, 0u, 0u, 0u};
        uint4* p = (uint4*)xs;
#pragma unroll
        for (int i = 0; i < 8; ++i) {
            int idx = tid + i * 256;
            if (idx < 2 * SLAB / 8) p[idx] = z;
        }
    }

    bool tOk[4];
    int  tSrc[4], tDst[4];
#pragma unroll
    for (int i = 0; i < 4; ++i) {
        int T = tid + i * 256;
        bool ex = (T < 792);
        int chh = T / 198, s = T - chh * 198;
        int row2 = s / 66, wp = s - row2 * 66;
        int gr = r - 1 + row2, gwc = wp - 1;
        tOk[i]  = ex && (gr >= 0) && (gr < 64) && (gwc >= 0) && (gwc < 64);
        tSrc[i] = ((b * 256 + chh * 8) * 64 + gr) * 64 + gwc;
        tDst[i] = (row2 * 66 + wp) * CSTR + chh * 8;
    }

    float tb[4][8];
    auto issueT = [&](int i, int dq) {
        if (tOk[i]) {
            const float* p = x + tSrc[i] + dq * 131072;
#pragma unroll
            for (int u = 0; u < 8; ++u) tb[i][u] = p[u * 4096];
        }
    };
    auto commitT = [&](int i, unsigned short* dst) {
        if (tOk[i]) {
            uint4 pk;
            pk.x = (unsigned)f2h_bits(tb[i][0]) | ((unsigned)f2h_bits(tb[i][1]) << 16);
            pk.y = (unsigned)f2h_bits(tb[i][2]) | ((unsigned)f2h_bits(tb[i][3]) << 16);
            pk.z = (unsigned)f2h_bits(tb[i][4]) | ((unsigned)f2h_bits(tb[i][5]) << 16);
            pk.w = (unsigned)f2h_bits(tb[i][6]) | ((unsigned)f2h_bits(tb[i][7]) << 16);
            *(uint4*)(dst + tDst[i]) = pk;
        }
    };

    const int ph = rw >> 1, eh = rw & 1;
    half8 Aa[3][2];
    uint4 Bb[3][2];
    auto prefA = [&](const unsigned short* buf, int t, int slot) {
        const int kh = t / 3, kw = t % 3;
        const unsigned short* abase =
            buf + (kh * 66 + ph * 32 + (lane & 15) + kw) * CSTR + (lane >> 4) * 8;
#pragma unroll
        for (int mt = 0; mt < 2; ++mt)
            Aa[slot][mt] = *(const half8*)(abase + mt * 16 * CSTR);
    };
    auto prefB = [&](int T9, int slot) {
        const uint4* bp = (const uint4*)wB + (T9 * 4 + eh * 2) * 64 + lane;
#pragma unroll
        for (int nt = 0; nt < 2; ++nt) Bb[slot][nt] = bp[nt * 64];
    };

    f32x4 acc[2][2];
#pragma unroll
    for (int mt = 0; mt < 2; ++mt)
#pragma unroll
        for (int nt = 0; nt < 2; ++nt) acc[mt][nt] = (f32x4){0.f, 0.f, 0.f, 0.f};

    auto mfma_tap = [&](int slot) {
#pragma unroll
        for (int nt = 0; nt < 2; ++nt) {
            half8 bfr;
            __builtin_memcpy(&bfr, &Bb[slot][nt], 16);
#pragma unroll
            for (int mt = 0; mt < 2; ++mt)
                acc[mt][nt] = __builtin_amdgcn_mfma_f32_16x16x32_f16(
                    Aa[slot][mt], bfr, acc[mt][nt], 0, 0, 0);
        }
    };

    __syncthreads();
    issueT(0, 0); issueT(1, 0); issueT(2, 0); issueT(3, 0);
    commitT(0, xs); commitT(1, xs); commitT(2, xs); commitT(3, xs);
    issueT(0, 1); issueT(1, 1); issueT(2, 1); issueT(3, 1);
    prefB(0, 0); prefB(1, 1); prefB(2, 2);
    __syncthreads();

#pragma unroll 1
    for (int q = 0; q < 8; ++q) {
        const unsigned short* cur = xs + (q & 1) * SLAB;
        unsigned short*       nxt = xs + ((q + 1) & 1) * SLAB;
        const int  T0  = q * 9;
        const bool cmt = (q < 7);
        const bool iss = (q < 6);

        prefA(cur, 0, 0); prefA(cur, 1, 1);
        mfma_tap(0); prefB(T0 + 3, 0); prefA(cur, 2, 2);
        mfma_tap(1); prefB(T0 + 4, 1); prefA(cur, 3, 0);
        if (cmt) { commitT(0, nxt); commitT(1, nxt); }
        mfma_tap(2); prefB(T0 + 5, 2); prefA(cur, 4, 1);
        mfma_tap(0); prefB(T0 + 6, 0); prefA(cur, 5, 2);
        if (cmt) { commitT(2, nxt); commitT(3, nxt); }
        mfma_tap(1); prefB(T0 + 7, 1); prefA(cur, 6, 0);
        mfma_tap(2); prefB(T0 + 8, 2); prefA(cur, 7, 1);
        __builtin_amdgcn_sched_barrier(0);
        if (iss) { issueT(0, q + 2); issueT(1, q + 2); issueT(2, q + 2); issueT(3, q + 2); }
        __builtin_amdgcn_sched_barrier(0);
        mfma_tap(0); if (cmt) prefB(T0 + 9, 0);  prefA(cur, 8, 2);
        mfma_tap(1); if (cmt) prefB(T0 + 10, 1);
        mfma_tap(2); if (cmt) prefB(T0 + 11, 2);
        __syncthreads();
    }

    float* scf2 = (float*)xs;
#pragma unroll
    for (int mt = 0; mt < 2; ++mt)
#pragma unroll
        for (int nt = 0; nt < 2; ++nt)
#pragma unroll
            for (int rr = 0; rr < 4; ++rr) {
                float v = acc[mt][nt][rr];
                float s = 1.f / (1.f + __builtin_amdgcn_exp2f(-v * LOG2E));
                int p = ph * 32 + mt * 16 + ((lane >> 4) << 2) + rr;
                int e = eh * 32 + nt * 16 + (lane & 15);
                scf2[p * SSTR + e] = s;
            }
    __syncthreads();

    if (tid < 64) {
        const float* row = scf2 + tid * SSTR;
        float tv[8];
        int   ti[8];
#pragma unroll
        for (int k = 0; k < 8; ++k) { tv[k] = -3.0e38f; ti[k] = 0; }
#pragma unroll
        for (int j4 = 0; j4 < 16; ++j4) {
            f32x4 blkv = *(const f32x4*)(row + j4 * 4);
#pragma unroll
            for (int j = 0; j < 4; ++j) {
                int   e  = j4 * 4 + j;
                float bs = blkv[j] + bias_s[e];
                if (bs > tv[7]) {
                    tv[7] = bs; ti[7] = e;
#pragma unroll
                    for (int k = 7; k > 0; --k) {
                        float fa = tv[k - 1], fb = tv[k];
                        int   ia = ti[k - 1], ib = ti[k];
                        bool  sw = fb > fa;
                        tv[k - 1] = sw ? fb : fa; tv[k] = sw ? fa : fb;
                        ti[k - 1] = sw ? ib : ia; ti[k] = sw ? ia : ib;
                    }
                }
            }
        }
        float u[8], mx = -3.0e38f;
#pragma unroll
        for (int k = 0; k < 8; ++k) { u[k] = tv[k] - bias_s[ti[k]]; mx = fmaxf(mx, u[k]); }
        float ex[8], sum = 0.f;
#pragma unroll
        for (int k = 0; k < 8; ++k) { ex[k] = __builtin_amdgcn_exp2f((u[k] - mx) * LOG2E); sum += ex[k]; }
        float inv = 1.f / sum;

        int obase = b * 32768 + r * 64 + tid;
#pragma unroll
        for (int k = 0; k < 8; ++k) {
            out[obase + k * 4096]          = ex[k] * inv;
            out[524288 + obase + k * 4096] = (float)ti[k];
            atomicAdd(&hist[ti[k]], 1);
        }
    }
    __syncthreads();
    if (tid < 64) atomicAdd(out + 1048576 + tid, (float)hist[tid]);
}

// ---------------------------------------------------------------------------
extern "C" void kernel_launch(void* const* d_in, const int* in_sizes, int n_in,
                              void* d_out, int out_size, void* d_ws, size_t ws_size,
                              hipStream_t stream) {
    const float* x    = (const float*)d_in[0];
    const float* gw   = (const float*)d_in[1];
    const float* bias = (const float*)d_in[2];
    float* out = (float*)d_out;

    if (ws_size >= WS_NEED) {
        _Float16* xT = (_Float16*)d_ws;
        unsigned short* wB = (unsigned short*)((char*)d_ws + XT_BYTES);
        prep_all2<<<PREP_GRID, 256, 0, stream>>>(x, gw, xT, wB, out);
        gate_main4<<<1024, 256, 0, stream>>>(xT, bias, wB, out);
    } else {
        unsigned short* wB = (unsigned short*)d_ws;
        gate_prep<<<72, 256, 0, stream>>>(gw, wB, out);
        gate_main_fb<<<1024, 256, 0, stream>>>(x, bias, wB, out);
    }
}